// Round 13
// baseline (165.825 us; speedup 1.0000x reference)
//
#include <hip/hip_runtime.h>

#define SIZE_D 512
#define HEADS  8
#define HDIM   64
#define BATCH  32
#define SEQ    512
#define SCALE_F 0.125f   // 1/sqrt(64)
#define NROWS  (BATCH * SEQ)   // 16384

typedef __attribute__((ext_vector_type(8))) short bf16x8;
typedef __attribute__((ext_vector_type(4))) float f32x4;
typedef __attribute__((ext_vector_type(4))) unsigned int u32x4;

__device__ __forceinline__ unsigned short f2bf(float f) {
    union { float f; unsigned int u; } c{f};
    unsigned int x = c.u;
    x += 0x7fffu + ((x >> 16) & 1u);   // RNE
    return (unsigned short)(x >> 16);
}
__device__ __forceinline__ float bf2f(unsigned short u) {
    union { unsigned int i; float f; } c;
    c.i = (unsigned int)u << 16;
    return c.f;
}
__device__ __forceinline__ unsigned int pack2bf(float lo, float hi) {
    // round-half-up bf16 pair pack
    return ((__float_as_uint(hi) + 0x8000u) & 0xffff0000u) |
           ((__float_as_uint(lo) + 0x8000u) >> 16);
}
__device__ __forceinline__ void gload_lds16(const unsigned short* g, unsigned short* l) {
    __builtin_amdgcn_global_load_lds(
        (const __attribute__((address_space(1))) unsigned int*)g,
        (__attribute__((address_space(3))) unsigned int*)l, 16, 0, 0);
}

// ---------------------------------------------------------------------------
// 4 weight matrices (512x512) -> contiguous bf16 [Wq;Wk;Wv;Wo]
// ---------------------------------------------------------------------------
__global__ __launch_bounds__(256) void cvt_w4(const float* __restrict__ w0,
                                              const float* __restrict__ w1,
                                              const float* __restrict__ w2,
                                              const float* __restrict__ w3,
                                              unsigned short* __restrict__ d) {
    const float* srcs[4] = {w0, w1, w2, w3};
    const float* s = srcs[blockIdx.y];
    unsigned short* dst = d + (size_t)blockIdx.y * (SIZE_D * SIZE_D);
    const int n = SIZE_D * SIZE_D;
    const int stride = gridDim.x * blockDim.x * 4;
    for (int i = (blockIdx.x * blockDim.x + threadIdx.x) * 4; i < n; i += stride) {
        const float4 v = *reinterpret_cast<const float4*>(s + i);
        ushort4 o;
        o.x = f2bf(v.x); o.y = f2bf(v.y); o.z = f2bf(v.z); o.w = f2bf(v.w);
        *reinterpret_cast<ushort4*>(dst + i) = o;
    }
}

// ---------------------------------------------------------------------------
// Merged projection GEMM, f32 A input, 2-DEEP A register pipeline.
// grid (128, 12): y 0..3 Q->Qh; y 4..7 K->Kh (pre-scaled); y 8..11 V->Vt.
// BK=32, LDS 32KB. (round-12 proven)
// ---------------------------------------------------------------------------
__global__ __launch_bounds__(256, 2) void gemm_proj3(const float* __restrict__ query,
                                                     const float* __restrict__ keyv,
                                                     const unsigned short* __restrict__ Wall,
                                                     const float* __restrict__ bq,
                                                     const float* __restrict__ bk,
                                                     const float* __restrict__ bv,
                                                     unsigned short* __restrict__ Qh,
                                                     unsigned short* __restrict__ Kh,
                                                     unsigned short* __restrict__ Vt) {
    __shared__ __align__(16) unsigned short Ad[2][128 * 32];   // 8KB x2
    __shared__ __align__(16) unsigned short Bd[2][128 * 32];   // 8KB x2

    const int tid  = threadIdx.x;
    const int wv   = tid >> 6;
    const int lane = tid & 63;
    const int y    = blockIdx.y;
    const int bm   = blockIdx.x * 128;
    const int bn   = y * 128;
    const int wr   = wv >> 1;
    const int wc   = wv & 1;

    const float* A = (y < 4) ? query : keyv;

    float4 areg[2][2][2];   // [slot][i][half] — 2-deep pipeline

    auto loadA = [&](int t, int slot) {
        const int k0 = t * 32;
#pragma unroll
        for (int i = 0; i < 2; ++i) {
            const int o   = i * 4096 + tid * 16;
            const int row = o >> 6;
            const int col = ((o & 63) ^ (((row >> 1) & 3) << 4)) >> 1;  // 0..31, mult of 8
            const float* src = A + (size_t)(bm + row) * SIZE_D + k0 + col;
            areg[slot][i][0] = *reinterpret_cast<const float4*>(src);
            areg[slot][i][1] = *reinterpret_cast<const float4*>(src + 4);
        }
    };
    auto writeA = [&](int buf, int slot) {
#pragma unroll
        for (int i = 0; i < 2; ++i) {
            const int o = i * 4096 + tid * 16;
            union { unsigned int u[4]; bf16x8 v; } pk;
            pk.u[0] = pack2bf(areg[slot][i][0].x, areg[slot][i][0].y);
            pk.u[1] = pack2bf(areg[slot][i][0].z, areg[slot][i][0].w);
            pk.u[2] = pack2bf(areg[slot][i][1].x, areg[slot][i][1].y);
            pk.u[3] = pack2bf(areg[slot][i][1].z, areg[slot][i][1].w);
            *reinterpret_cast<bf16x8*>(&Ad[buf][o >> 1]) = pk.v;
        }
    };
    auto stageW = [&](int buf, int t) {
        const int k0 = t * 32;
#pragma unroll
        for (int i = 0; i < 2; ++i) {
            const int o   = i * 4096 + tid * 16;
            const int row = o >> 6;
            const int col = ((o & 63) ^ (((row >> 1) & 3) << 4)) >> 1;
            gload_lds16(Wall + (size_t)(bn + row) * SIZE_D + k0 + col, &Bd[buf][o >> 1]);
        }
    };

    f32x4 acc[4][4];
#pragma unroll
    for (int mt = 0; mt < 4; ++mt)
#pragma unroll
        for (int nt = 0; nt < 4; ++nt) acc[mt][nt] = (f32x4){0.f, 0.f, 0.f, 0.f};

    // prologue: tile0 -> slot0 -> Ad[0]; tile1 -> slot1 (pending)
    loadA(0, 0);
    stageW(0, 0);
    writeA(0, 0);
    loadA(1, 1);
    __syncthreads();
    int cur = 0;

    for (int t = 0; t < 16; ++t) {
        if (t < 14) loadA(t + 2, t & 1);
        if (t < 15) stageW(cur ^ 1, t + 1);

        bf16x8 af[4], bfr[4];
#pragma unroll
        for (int mt = 0; mt < 4; ++mt) {
            const int r = wr * 64 + mt * 16 + (lane & 15);
            int byte = r * 64 + (lane >> 4) * 16;
            byte ^= ((r >> 1) & 3) << 4;
            af[mt] = *reinterpret_cast<const bf16x8*>(
                reinterpret_cast<const char*>(&Ad[cur][0]) + byte);
        }
#pragma unroll
        for (int nt = 0; nt < 4; ++nt) {
            const int r = wc * 64 + nt * 16 + (lane & 15);
            int byte = r * 64 + (lane >> 4) * 16;
            byte ^= ((r >> 1) & 3) << 4;
            bfr[nt] = *reinterpret_cast<const bf16x8*>(
                reinterpret_cast<const char*>(&Bd[cur][0]) + byte);
        }
#pragma unroll
        for (int mt = 0; mt < 4; ++mt)
#pragma unroll
            for (int nt = 0; nt < 4; ++nt)
                acc[mt][nt] = __builtin_amdgcn_mfma_f32_16x16x32_bf16(
                    af[mt], bfr[nt], acc[mt][nt], 0, 0, 0);

        if (t < 15) writeA(cur ^ 1, (t + 1) & 1);
        __syncthreads();
        cur ^= 1;
    }

    if (y < 8) {
        const float* bias = (y < 4) ? bq : bk;
        unsigned short* D = (y < 4) ? Qh : Kh;
        const int coff = (y < 4) ? 0 : 512;
#pragma unroll
        for (int nt = 0; nt < 4; ++nt) {
            const int colL = bn - coff + wc * 64 + nt * 16 + (lane & 15);
            const float bc = bias[colL];
            const int h = colL >> 6, dd = colL & 63;
#pragma unroll
            for (int mt = 0; mt < 4; ++mt) {
                const int row0 = bm + wr * 64 + mt * 16 + (lane >> 4) * 4;
#pragma unroll
                for (int r = 0; r < 4; ++r) {
                    const int row = row0 + r;
                    const int b_ = row >> 9, l = row & 511;
                    float z = acc[mt][nt][r] + bc;
                    if (y >= 4) z *= SCALE_F;
                    D[(((size_t)b_ * HEADS + h) * SEQ + l) * HDIM + dd] = f2bf(z);
                }
            }
        }
    } else {
#pragma unroll
        for (int nt = 0; nt < 4; ++nt) {
            const int c2 = bn - 1024 + wc * 64 + nt * 16 + (lane & 15);
            const float bc = bv[c2];
            const int hV = c2 >> 6, dV = c2 & 63;
#pragma unroll
            for (int mt = 0; mt < 4; ++mt) {
                const int row0 = bm + wr * 64 + mt * 16 + (lane >> 4) * 4;
                const int b_ = row0 >> 9, kv = row0 & 511;
                ushort4 pk;
                pk.x = f2bf(acc[mt][nt][0] + bc);
                pk.y = f2bf(acc[mt][nt][1] + bc);
                pk.z = f2bf(acc[mt][nt][2] + bc);
                pk.w = f2bf(acc[mt][nt][3] + bc);
                *reinterpret_cast<ushort4*>(
                    &Vt[(((size_t)b_ * HEADS + hV) * HDIM + dV) * SEQ + kv]) = pk;
            }
        }
    }
}

// ---------------------------------------------------------------------------
// MFMA attention — q-split for occupancy: grid (bh, 4), 256 thr = 4 waves x
// 32 q-rows, LB(256,2) (NO VGPR clamp — r7's replay failure was the LB(256,4)
// spill regime). 32KB LDS dbuf -> 4 blocks/CU. In-register P, permuted PV.
// ---------------------------------------------------------------------------
__global__ __launch_bounds__(256, 2) void attn_mfma(const unsigned short* __restrict__ Qh,
                                                    const unsigned short* __restrict__ Kh,
                                                    const unsigned short* __restrict__ Vt,
                                                    float* __restrict__ outq) {
    __shared__ __align__(16) unsigned short Kt[2][64 * 64];   // [kv][d] swizzled
    __shared__ __align__(16) unsigned short Vs[2][64 * 64];   // [d][kv] swizzled

    const int tid  = threadIdx.x;
    const int wv   = tid >> 6;
    const int lane = tid & 63;
    const int bh   = blockIdx.x;
    const int b    = bh >> 3;
    const int h    = bh & 7;
    const int g    = lane >> 4;

    const unsigned short* Qb = Qh + (size_t)bh * (SEQ * HDIM);
    const unsigned short* Kb = Kh + (size_t)bh * (SEQ * HDIM);
    const unsigned short* Vb = Vt + (size_t)bh * (HDIM * SEQ);

    const int m0 = blockIdx.y * 128 + wv * 32;

    auto stageKV = [&](int buf, int t) {
        const int kv0 = t * 64;
#pragma unroll
        for (int i = 0; i < 2; ++i) {
            const int o   = i * 4096 + tid * 16;
            const int row = o >> 7;
            const int in  = (o & 127) ^ ((row & 7) << 4);
            gload_lds16(Kb + (size_t)(kv0 + row) * HDIM + (in >> 1), &Kt[buf][o >> 1]);
            gload_lds16(Vb + (size_t)row * SEQ + kv0 + (in >> 1), &Vs[buf][o >> 1]);
        }
    };

    // Q fragments (A/B-frag layout: row=lane&15, k=8*g+j)
    bf16x8 qf[2][2];
#pragma unroll
    for (int mt = 0; mt < 2; ++mt)
#pragma unroll
        for (int kc = 0; kc < 2; ++kc) {
            const int m = m0 + mt * 16 + (lane & 15);
            union { u32x4 u; bf16x8 v; } cv;
            cv.u = *reinterpret_cast<const u32x4*>(
                Qb + (size_t)m * HDIM + kc * 32 + g * 8);
            qf[mt][kc] = cv.v;
        }

    f32x4 oacc[2][4];
    float esum[2] = {0.f, 0.f};
#pragma unroll
    for (int mt = 0; mt < 2; ++mt)
#pragma unroll
        for (int x = 0; x < 4; ++x) oacc[mt][x] = (f32x4){0.f, 0.f, 0.f, 0.f};

    stageKV(0, 0);
    __syncthreads();
    int cur = 0;

    for (int t = 0; t < 8; ++t) {
        if (t < 7) stageKV(cur ^ 1, t + 1);

        // ---- QK^T: sacc[nt][mt]; lane holds q=lane&15, kv=16nt+4g+r ----
        f32x4 sacc[4][2];
#pragma unroll
        for (int nt = 0; nt < 4; ++nt)
#pragma unroll
            for (int mt = 0; mt < 2; ++mt) sacc[nt][mt] = (f32x4){0.f, 0.f, 0.f, 0.f};

#pragma unroll
        for (int kc = 0; kc < 2; ++kc) {
            bf16x8 kf[4];
#pragma unroll
            for (int nt = 0; nt < 4; ++nt) {
                const int kvl = nt * 16 + (lane & 15);
                int byte = kvl * 128 + kc * 64 + g * 16;
                byte ^= (kvl & 7) << 4;
                kf[nt] = *reinterpret_cast<const bf16x8*>(
                    reinterpret_cast<const char*>(&Kt[cur][0]) + byte);
            }
#pragma unroll
            for (int nt = 0; nt < 4; ++nt)
#pragma unroll
                for (int mt = 0; mt < 2; ++mt)
                    sacc[nt][mt] = __builtin_amdgcn_mfma_f32_16x16x32_bf16(
                        kf[nt], qf[mt][kc], sacc[nt][mt], 0, 0, 0);
        }

        // ---- transform in-register -> pa[c][mt] (A-frags for PV) ----
        // k-slot j of pa[c][mt] carries kv = 16*(2c+(j>>2)) + 4g + (j&3)
        bf16x8 pa[2][2];
#pragma unroll
        for (int c = 0; c < 2; ++c)
#pragma unroll
            for (int mt = 0; mt < 2; ++mt) {
                float w[8];
#pragma unroll
                for (int j = 0; j < 8; ++j) {
                    const float s  = sacc[2 * c + (j >> 2)][mt][j & 3];
                    const float a  = fminf(fabsf(s), 30.0f);
                    const float tt = __expf(a);
                    const float t2 = tt * tt;
                    const float u  = __builtin_amdgcn_sqrtf(fmaf(s, s, 0.01f));
                    const float dl = u - a;
                    const float ed = fmaf(dl, fmaf(dl, fmaf(dl, 0.16666667f, 0.5f), 1.0f), 1.0f);
                    const float eu = tt * ed;
                    esum[mt] += eu;
                    const float th = (t2 - 1.0f) * __builtin_amdgcn_rcpf(t2 + 1.0f);
                    w[j] = __builtin_copysignf(th * eu, s);
                }
                union { unsigned int u[4]; bf16x8 v; } pk;
#pragma unroll
                for (int p = 0; p < 4; ++p)
                    pk.u[p] = (__float_as_uint(w[2 * p + 1]) & 0xffff0000u) |
                              (__float_as_uint(w[2 * p]) >> 16);
                pa[c][mt] = pk.v;
            }

        // ---- PV with permuted B-frags from swizzled Vs ----
#pragma unroll
        for (int c = 0; c < 2; ++c) {
            bf16x8 vf[4];
#pragma unroll
            for (int dt = 0; dt < 4; ++dt) {
                const int d = dt * 16 + (lane & 15);
                const int swz = (d & 7) << 4;
                const int rowb = d * 128;
                uint2 lo = *reinterpret_cast<const uint2*>(
                    reinterpret_cast<const char*>(&Vs[cur][0]) +
                    (rowb + (((c * 32 + 4 * g) * 2) ^ swz)));
                uint2 hi = *reinterpret_cast<const uint2*>(
                    reinterpret_cast<const char*>(&Vs[cur][0]) +
                    (rowb + (((c * 32 + 16 + 4 * g) * 2) ^ swz)));
                union { unsigned int u[4]; bf16x8 v; } cvb;
                cvb.u[0] = lo.x; cvb.u[1] = lo.y;
                cvb.u[2] = hi.x; cvb.u[3] = hi.y;
                vf[dt] = cvb.v;
            }
#pragma unroll
            for (int mt = 0; mt < 2; ++mt)
#pragma unroll
                for (int dt = 0; dt < 4; ++dt)
                    oacc[mt][dt] = __builtin_amdgcn_mfma_f32_16x16x32_bf16(
                        pa[c][mt], vf[dt], oacc[mt][dt], 0, 0, 0);
        }

        __syncthreads();
        cur ^= 1;
    }

    // ---- epilogue: reduce esum, redistribute, normalize, residual ----
    float rden[2];
#pragma unroll
    for (int mt = 0; mt < 2; ++mt) {
        float e = esum[mt];
        e += __shfl_xor(e, 16);
        e += __shfl_xor(e, 32);
        rden[mt] = __builtin_amdgcn_rcpf(e);
    }
    float rr_[2][4];
#pragma unroll
    for (int mt = 0; mt < 2; ++mt)
#pragma unroll
        for (int r = 0; r < 4; ++r)
            rr_[mt][r] = __shfl(rden[mt], g * 4 + r);

#pragma unroll
    for (int mt = 0; mt < 2; ++mt)
#pragma unroll
        for (int dt = 0; dt < 4; ++dt)
#pragma unroll
            for (int r = 0; r < 4; ++r) {
                const int m = m0 + mt * 16 + g * 4 + r;
                const int d = dt * 16 + (lane & 15);
                const float qv = bf2f(Qb[(size_t)m * HDIM + d]);
                outq[((size_t)b * SEQ + m) * SIZE_D + h * HDIM + d] =
                    qv + oacc[mt][dt][r] * rr_[mt][r];
            }
}

// ---------------------------------------------------------------------------
// LN0: f32 in -> bf16 out (serves as GEMM-A and residual R)
// ---------------------------------------------------------------------------
__global__ __launch_bounds__(256) void ln0_bf16(const float* __restrict__ in,
                                                const float* __restrict__ w,
                                                const float* __restrict__ b,
                                                unsigned short* __restrict__ outb) {
    const int row = blockIdx.x;
    const int tid = threadIdx.x;
    const float2 x = *reinterpret_cast<const float2*>(&in[(size_t)row * SIZE_D + tid * 2]);

    float s  = x.x + x.y;
    float sq = x.x * x.x + x.y * x.y;
#pragma unroll
    for (int off = 32; off > 0; off >>= 1) {
        s  += __shfl_xor(s, off);
        sq += __shfl_xor(sq, off);
    }
    __shared__ float rs[4], rq[4];
    const int wv = tid >> 6;
    if ((tid & 63) == 0) { rs[wv] = s; rq[wv] = sq; }
    __syncthreads();
    s  = rs[0] + rs[1] + rs[2] + rs[3];
    sq = rq[0] + rq[1] + rq[2] + rq[3];

    const float mu  = s * (1.0f / SIZE_D);
    const float var = sq * (1.0f / SIZE_D) - mu * mu;
    const float rr  = rsqrtf(var + 1e-5f);

    const float2 wv2 = *reinterpret_cast<const float2*>(&w[tid * 2]);
    const float2 bv2 = *reinterpret_cast<const float2*>(&b[tid * 2]);
    ushort2 ob;
    ob.x = f2bf((x.x - mu) * rr * wv2.x + bv2.x);
    ob.y = f2bf((x.y - mu) * rr * wv2.y + bv2.y);
    *reinterpret_cast<ushort2*>(&outb[(size_t)row * SIZE_D + tid * 2]) = ob;
}

// ---------------------------------------------------------------------------
// Fused out-proj + ReLU + residual + LN1 -> d_out. BK=32, 2 blocks/CU.
// ---------------------------------------------------------------------------
__global__ __launch_bounds__(512, 2) void oproj_ln(const unsigned short* __restrict__ X,
                                                   const unsigned short* __restrict__ W,
                                                   const float* __restrict__ bo,
                                                   const float* __restrict__ g1,
                                                   const float* __restrict__ b1,
                                                   float* __restrict__ out) {
    __shared__ __align__(16) unsigned short Ad[2][64 * 32];
    __shared__ __align__(16) unsigned short Bd[2][512 * 32];
    __shared__ float red[64][8][2];
    __shared__ float stat[64][2];

    const int tid  = threadIdx.x;
    const int wv   = tid >> 6;
    const int lane = tid & 63;
    const int bm   = blockIdx.x * 64;

    auto stage = [&](int buf, int t) {
        const int k0 = t * 32;
        if (tid < 256) {
            const int o   = tid * 16;
            const int row = o >> 6;
            const int in  = (o & 63) ^ (((row >> 1) & 3) << 4);
            gload_lds16(X + (size_t)(bm + row) * SIZE_D + k0 + (in >> 1), &Ad[buf][o >> 1]);
        }
#pragma unroll
        for (int i = 0; i < 4; ++i) {
            const int o   = i * 8192 + tid * 16;
            const int row = o >> 6;
            const int in  = (o & 63) ^ (((row >> 1) & 3) << 4);
            gload_lds16(W + (size_t)row * SIZE_D + k0 + (in >> 1), &Bd[buf][o >> 1]);
        }
    };

    f32x4 acc[4][4];
#pragma unroll
    for (int mt = 0; mt < 4; ++mt)
#pragma unroll
        for (int nt = 0; nt < 4; ++nt) acc[mt][nt] = (f32x4){0.f, 0.f, 0.f, 0.f};

    stage(0, 0);
    __syncthreads();
    int cur = 0;

    for (int t = 0; t < 16; ++t) {
        if (t < 15) stage(cur ^ 1, t + 1);

        bf16x8 af[4], bfr[4];
#pragma unroll
        for (int mt = 0; mt < 4; ++mt) {
            const int r = mt * 16 + (lane & 15);
            int byte = r * 64 + (lane >> 4) * 16;
            byte ^= ((r >> 1) & 3) << 4;
            af[mt] = *reinterpret_cast<const bf16x8*>(
                reinterpret_cast<const char*>(&Ad[cur][0]) + byte);
        }
#pragma unroll
        for (int nt = 0; nt < 4; ++nt) {
            const int r = wv * 64 + nt * 16 + (lane & 15);
            int byte = r * 64 + (lane >> 4) * 16;
            byte ^= ((r >> 1) & 3) << 4;
            bfr[nt] = *reinterpret_cast<const bf16x8*>(
                reinterpret_cast<const char*>(&Bd[cur][0]) + byte);
        }
#pragma unroll
        for (int mt = 0; mt < 4; ++mt)
#pragma unroll
            for (int nt = 0; nt < 4; ++nt)
                acc[mt][nt] = __builtin_amdgcn_mfma_f32_16x16x32_bf16(
                    af[mt], bfr[nt], acc[mt][nt], 0, 0, 0);

        __syncthreads();
        cur ^= 1;
    }

#pragma unroll
    for (int nt = 0; nt < 4; ++nt) {
        const int n  = wv * 64 + nt * 16 + (lane & 15);
        const float bc = bo[n];
#pragma unroll
        for (int mt = 0; mt < 4; ++mt) {
            const int row0 = bm + mt * 16 + (lane >> 4) * 4;
#pragma unroll
            for (int r = 0; r < 4; ++r) {
                const float R = bf2f(X[(size_t)(row0 + r) * SIZE_D + n]);
                acc[mt][nt][r] = R + fmaxf(acc[mt][nt][r] + bc, 0.0f);
            }
        }
    }

    float ps[4][4], pq[4][4];
#pragma unroll
    for (int mt = 0; mt < 4; ++mt)
#pragma unroll
        for (int r = 0; r < 4; ++r) {
            float s = 0.f, q = 0.f;
#pragma unroll
            for (int nt = 0; nt < 4; ++nt) {
                const float v = acc[mt][nt][r];
                s += v; q += v * v;
            }
#pragma unroll
            for (int off = 1; off <= 8; off <<= 1) {
                s += __shfl_xor(s, off);
                q += __shfl_xor(q, off);
            }
            ps[mt][r] = s; pq[mt][r] = q;
        }
    {
        const int mtw = (lane & 15) >> 2, rw = lane & 3;
        const int rowL = mtw * 16 + (lane >> 4) * 4 + rw;
        red[rowL][wv][0] = ps[mtw][rw];
        red[rowL][wv][1] = pq[mtw][rw];
    }
    __syncthreads();
    if (tid < 64) {
        float s = 0.f, q = 0.f;
#pragma unroll
        for (int w8 = 0; w8 < 8; ++w8) { s += red[tid][w8][0]; q += red[tid][w8][1]; }
        const float mu  = s * (1.0f / SIZE_D);
        const float var = q * (1.0f / SIZE_D) - mu * mu;
        stat[tid][0] = mu;
        stat[tid][1] = rsqrtf(var + 1e-5f);
    }
    __syncthreads();

#pragma unroll
    for (int nt = 0; nt < 4; ++nt) {
        const int n = wv * 64 + nt * 16 + (lane & 15);
        const float g = g1[n], bb = b1[n];
#pragma unroll
        for (int mt = 0; mt < 4; ++mt) {
#pragma unroll
            for (int r = 0; r < 4; ++r) {
                const int rowL = mt * 16 + (lane >> 4) * 4 + r;
                const float y = (acc[mt][nt][r] - stat[rowL][0]) * stat[rowL][1];
                out[(size_t)(bm + rowL) * SIZE_D + n] = y * g + bb;
            }
        }
    }
}

// ---------------------------------------------------------------------------
extern "C" void kernel_launch(void* const* d_in, const int* in_sizes, int n_in,
                              void* d_out, int out_size, void* d_ws, size_t ws_size,
                              hipStream_t stream) {
    const float* query = (const float*)d_in[0];
    const float* keyv  = (const float*)d_in[1];
    const float* Wq    = (const float*)d_in[2];
    const float* bq    = (const float*)d_in[3];
    const float* Wk    = (const float*)d_in[4];
    const float* bk    = (const float*)d_in[5];
    const float* Wv    = (const float*)d_in[6];
    const float* bv    = (const float*)d_in[7];
    const float* Wo    = (const float*)d_in[8];
    const float* bo    = (const float*)d_in[9];
    const float* ln0w  = (const float*)d_in[10];
    const float* ln0b  = (const float*)d_in[11];
    const float* ln1w  = (const float*)d_in[12];
    const float* ln1b  = (const float*)d_in[13];
    float* out = (float*)d_out;

    // workspace layout:
    //   [ 0,32) qbuf f32 (attn output)
    //   [32,48) Qh bf16 head-major -> Xbf bf16 after ln0
    //   [48,64) Kh bf16 head-major (pre-scaled)
    //   [64,80) Vt bf16 transposed [b,h,d,kv]
    //   [80,82) Wbf: [Wq;Wk;Wv;Wo] bf16 contiguous
    char* ws = (char*)d_ws;
    float*          qbuf = (float*)ws;
    unsigned short* Qh   = (unsigned short*)(ws + ((size_t)32 << 20));
    unsigned short* Xbf  = Qh;
    unsigned short* Kh   = (unsigned short*)(ws + ((size_t)48 << 20));
    unsigned short* Vt   = (unsigned short*)(ws + ((size_t)64 << 20));
    unsigned short* Wbf  = (unsigned short*)(ws + ((size_t)80 << 20));
    unsigned short* WoB  = Wbf + 786432;

    cvt_w4<<<dim3(64, 4), 256, 0, stream>>>(Wq, Wk, Wv, Wo, Wbf);

    gemm_proj3<<<dim3(128, 12), 256, 0, stream>>>(query, keyv, Wbf, bq, bk, bv, Qh, Kh, Vt);

    attn_mfma<<<dim3(BATCH * HEADS, 4), 256, 0, stream>>>(Qh, Kh, Vt, qbuf);

    ln0_bf16<<<NROWS, 256, 0, stream>>>(qbuf, ln0w, ln0b, Xbf);

    oproj_ln<<<NROWS / 64, 512, 0, stream>>>(Xbf, WoB, bo, ln1w, ln1b, out);
}

// Round 14
// 160.743 us; speedup vs baseline: 1.0316x; 1.0316x over previous
//
#include <hip/hip_runtime.h>

#define SIZE_D 512
#define HEADS  8
#define HDIM   64
#define BATCH  32
#define SEQ    512
#define SCALE_F 0.125f   // 1/sqrt(64)
#define NROWS  (BATCH * SEQ)   // 16384

typedef __attribute__((ext_vector_type(8))) short bf16x8;
typedef __attribute__((ext_vector_type(4))) float f32x4;
typedef __attribute__((ext_vector_type(4))) unsigned int u32x4;

__device__ __forceinline__ unsigned short f2bf(float f) {
    union { float f; unsigned int u; } c{f};
    unsigned int x = c.u;
    x += 0x7fffu + ((x >> 16) & 1u);   // RNE
    return (unsigned short)(x >> 16);
}
__device__ __forceinline__ float bf2f(unsigned short u) {
    union { unsigned int i; float f; } c;
    c.i = (unsigned int)u << 16;
    return c.f;
}
__device__ __forceinline__ unsigned int pack2bf(float lo, float hi) {
    // round-half-up bf16 pair pack
    return ((__float_as_uint(hi) + 0x8000u) & 0xffff0000u) |
           ((__float_as_uint(lo) + 0x8000u) >> 16);
}
__device__ __forceinline__ void gload_lds16(const unsigned short* g, unsigned short* l) {
    __builtin_amdgcn_global_load_lds(
        (const __attribute__((address_space(1))) unsigned int*)g,
        (__attribute__((address_space(3))) unsigned int*)l, 16, 0, 0);
}

// ---------------------------------------------------------------------------
// 4 weight matrices (512x512) -> contiguous bf16 [Wq;Wk;Wv;Wo]
// ---------------------------------------------------------------------------
__global__ __launch_bounds__(256) void cvt_w4(const float* __restrict__ w0,
                                              const float* __restrict__ w1,
                                              const float* __restrict__ w2,
                                              const float* __restrict__ w3,
                                              unsigned short* __restrict__ d) {
    const float* srcs[4] = {w0, w1, w2, w3};
    const float* s = srcs[blockIdx.y];
    unsigned short* dst = d + (size_t)blockIdx.y * (SIZE_D * SIZE_D);
    const int n = SIZE_D * SIZE_D;
    const int stride = gridDim.x * blockDim.x * 4;
    for (int i = (blockIdx.x * blockDim.x + threadIdx.x) * 4; i < n; i += stride) {
        const float4 v = *reinterpret_cast<const float4*>(s + i);
        ushort4 o;
        o.x = f2bf(v.x); o.y = f2bf(v.y); o.z = f2bf(v.z); o.w = f2bf(v.w);
        *reinterpret_cast<ushort4*>(dst + i) = o;
    }
}

// ---------------------------------------------------------------------------
// Merged projection GEMM, f32 A input, BK=64 + 2-DEEP A register pipeline.
// grid (128, 12): y 0..3 Q->Qh; y 4..7 K->Kh (pre-scaled); y 8..11 V->Vt.
// Step t: loadA(t+2) BEFORE the 32 MFMAs (step compute ~500cy, so 2-step
// distance ~1000cy covers HBM); writeA(t+1) AFTER. 8 barrier-drains (vs 16).
// 128B-row swizzle byte ^= (row&7)<<4 (r3-proven). W: global_load_lds bf16.
// ---------------------------------------------------------------------------
__global__ __launch_bounds__(256, 2) void gemm_proj3(const float* __restrict__ query,
                                                     const float* __restrict__ keyv,
                                                     const unsigned short* __restrict__ Wall,
                                                     const float* __restrict__ bq,
                                                     const float* __restrict__ bk,
                                                     const float* __restrict__ bv,
                                                     unsigned short* __restrict__ Qh,
                                                     unsigned short* __restrict__ Kh,
                                                     unsigned short* __restrict__ Vt) {
    __shared__ __align__(16) unsigned short Ad[2][128 * 64];   // 16KB x2
    __shared__ __align__(16) unsigned short Bd[2][128 * 64];   // 16KB x2

    const int tid  = threadIdx.x;
    const int wv   = tid >> 6;
    const int lane = tid & 63;
    const int y    = blockIdx.y;
    const int bm   = blockIdx.x * 128;
    const int bn   = y * 128;
    const int wr   = wv >> 1;
    const int wc   = wv & 1;

    const float* A = (y < 4) ? query : keyv;

    float4 areg[2][4][2];   // [slot][i][half] — 2-deep pipeline, 64 VGPRs

    auto loadA = [&](int t, int slot) {
        const int k0 = t * 64;
#pragma unroll
        for (int i = 0; i < 4; ++i) {
            const int o   = (wv * 32 + i * 8) * 128 + lane * 16;
            const int row = o >> 7;
            const int col = ((o & 127) ^ ((row & 7) << 4)) >> 1;   // 0..63, mult of 8
            const float* src = A + (size_t)(bm + row) * SIZE_D + k0 + col;
            areg[slot][i][0] = *reinterpret_cast<const float4*>(src);
            areg[slot][i][1] = *reinterpret_cast<const float4*>(src + 4);
        }
    };
    auto writeA = [&](int buf, int slot) {
#pragma unroll
        for (int i = 0; i < 4; ++i) {
            const int o = (wv * 32 + i * 8) * 128 + lane * 16;
            union { unsigned int u[4]; bf16x8 v; } pk;
            pk.u[0] = pack2bf(areg[slot][i][0].x, areg[slot][i][0].y);
            pk.u[1] = pack2bf(areg[slot][i][0].z, areg[slot][i][0].w);
            pk.u[2] = pack2bf(areg[slot][i][1].x, areg[slot][i][1].y);
            pk.u[3] = pack2bf(areg[slot][i][1].z, areg[slot][i][1].w);
            *reinterpret_cast<bf16x8*>(&Ad[buf][o >> 1]) = pk.v;
        }
    };
    auto stageW = [&](int buf, int t) {
        const int k0 = t * 64;
#pragma unroll
        for (int i = 0; i < 4; ++i) {
            const int o   = (wv * 32 + i * 8) * 128 + lane * 16;
            const int row = o >> 7;
            const int col = ((o & 127) ^ ((row & 7) << 4)) >> 1;
            gload_lds16(Wall + (size_t)(bn + row) * SIZE_D + k0 + col, &Bd[buf][o >> 1]);
        }
    };

    f32x4 acc[4][4];
#pragma unroll
    for (int mt = 0; mt < 4; ++mt)
#pragma unroll
        for (int nt = 0; nt < 4; ++nt) acc[mt][nt] = (f32x4){0.f, 0.f, 0.f, 0.f};

    // prologue: tile0 -> slot0 -> Ad[0]; tile1 -> slot1 (pending)
    loadA(0, 0);
    stageW(0, 0);
    writeA(0, 0);
    loadA(1, 1);
    __syncthreads();
    int cur = 0;

    for (int t = 0; t < 8; ++t) {
        if (t < 6) loadA(t + 2, t & 1);          // 2-step load->use distance
        if (t < 7) stageW(cur ^ 1, t + 1);

        bf16x8 af[2][4], bfr[2][4];
#pragma unroll
        for (int kc = 0; kc < 2; ++kc) {
#pragma unroll
            for (int mt = 0; mt < 4; ++mt) {
                const int r = wr * 64 + mt * 16 + (lane & 15);
                int byte = r * 128 + kc * 64 + (lane >> 4) * 16;
                byte ^= (r & 7) << 4;
                af[kc][mt] = *reinterpret_cast<const bf16x8*>(
                    reinterpret_cast<const char*>(&Ad[cur][0]) + byte);
            }
#pragma unroll
            for (int nt = 0; nt < 4; ++nt) {
                const int r = wc * 64 + nt * 16 + (lane & 15);
                int byte = r * 128 + kc * 64 + (lane >> 4) * 16;
                byte ^= (r & 7) << 4;
                bfr[kc][nt] = *reinterpret_cast<const bf16x8*>(
                    reinterpret_cast<const char*>(&Bd[cur][0]) + byte);
            }
        }
#pragma unroll
        for (int kc = 0; kc < 2; ++kc)
#pragma unroll
            for (int mt = 0; mt < 4; ++mt)
#pragma unroll
                for (int nt = 0; nt < 4; ++nt)
                    acc[mt][nt] = __builtin_amdgcn_mfma_f32_16x16x32_bf16(
                        af[kc][mt], bfr[kc][nt], acc[mt][nt], 0, 0, 0);

        if (t < 7) writeA(cur ^ 1, (t + 1) & 1);   // cvt + ds_write after MFMAs
        __syncthreads();
        cur ^= 1;
    }

    if (y < 8) {
        const float* bias = (y < 4) ? bq : bk;
        unsigned short* D = (y < 4) ? Qh : Kh;
        const int coff = (y < 4) ? 0 : 512;
#pragma unroll
        for (int nt = 0; nt < 4; ++nt) {
            const int colL = bn - coff + wc * 64 + nt * 16 + (lane & 15);
            const float bc = bias[colL];
            const int h = colL >> 6, dd = colL & 63;
#pragma unroll
            for (int mt = 0; mt < 4; ++mt) {
                const int row0 = bm + wr * 64 + mt * 16 + (lane >> 4) * 4;
#pragma unroll
                for (int r = 0; r < 4; ++r) {
                    const int row = row0 + r;
                    const int b_ = row >> 9, l = row & 511;
                    float z = acc[mt][nt][r] + bc;
                    if (y >= 4) z *= SCALE_F;
                    D[(((size_t)b_ * HEADS + h) * SEQ + l) * HDIM + dd] = f2bf(z);
                }
            }
        }
    } else {
#pragma unroll
        for (int nt = 0; nt < 4; ++nt) {
            const int c2 = bn - 1024 + wc * 64 + nt * 16 + (lane & 15);
            const float bc = bv[c2];
            const int hV = c2 >> 6, dV = c2 & 63;
#pragma unroll
            for (int mt = 0; mt < 4; ++mt) {
                const int row0 = bm + wr * 64 + mt * 16 + (lane >> 4) * 4;
                const int b_ = row0 >> 9, kv = row0 & 511;
                ushort4 pk;
                pk.x = f2bf(acc[mt][nt][0] + bc);
                pk.y = f2bf(acc[mt][nt][1] + bc);
                pk.z = f2bf(acc[mt][nt][2] + bc);
                pk.w = f2bf(acc[mt][nt][3] + bc);
                *reinterpret_cast<ushort4*>(
                    &Vt[(((size_t)b_ * HEADS + hV) * HDIM + dV) * SEQ + kv]) = pk;
            }
        }
    }
}

// ---------------------------------------------------------------------------
// MFMA attention — round-8/12 proven shell: grid (bh,2), 256 thr = 4 waves x
// 64 q, LB(256,2), 32KB LDS dbuf, in-register P, permuted PV B-frags.
// (q-split variants r9/r13 both regressed: staging duplication cancels
//  occupancy; VALUBusy caps ~58% regardless. Do not re-split.)
// ---------------------------------------------------------------------------
__global__ __launch_bounds__(256, 2) void attn_mfma(const unsigned short* __restrict__ Qh,
                                                    const unsigned short* __restrict__ Kh,
                                                    const unsigned short* __restrict__ Vt,
                                                    float* __restrict__ outq) {
    __shared__ __align__(16) unsigned short Kt[2][64 * 64];   // [kv][d] swizzled
    __shared__ __align__(16) unsigned short Vs[2][64 * 64];   // [d][kv] swizzled

    const int tid  = threadIdx.x;
    const int wv   = tid >> 6;
    const int lane = tid & 63;
    const int bh   = blockIdx.x;
    const int b    = bh >> 3;
    const int h    = bh & 7;
    const int g    = lane >> 4;

    const unsigned short* Qb = Qh + (size_t)bh * (SEQ * HDIM);
    const unsigned short* Kb = Kh + (size_t)bh * (SEQ * HDIM);
    const unsigned short* Vb = Vt + (size_t)bh * (HDIM * SEQ);

    const int m0 = blockIdx.y * 256 + wv * 64;

    auto stageKV = [&](int buf, int t) {
        const int kv0 = t * 64;
#pragma unroll
        for (int i = 0; i < 2; ++i) {
            const int o   = i * 4096 + tid * 16;
            const int row = o >> 7;
            const int in  = (o & 127) ^ ((row & 7) << 4);
            gload_lds16(Kb + (size_t)(kv0 + row) * HDIM + (in >> 1), &Kt[buf][o >> 1]);
            gload_lds16(Vb + (size_t)row * SEQ + kv0 + (in >> 1), &Vs[buf][o >> 1]);
        }
    };

    // Q fragments (A/B-frag layout: row=lane&15, k=8*g+j)
    bf16x8 qf[4][2];
#pragma unroll
    for (int mt = 0; mt < 4; ++mt)
#pragma unroll
        for (int kc = 0; kc < 2; ++kc) {
            const int m = m0 + mt * 16 + (lane & 15);
            union { u32x4 u; bf16x8 v; } cv;
            cv.u = *reinterpret_cast<const u32x4*>(
                Qb + (size_t)m * HDIM + kc * 32 + g * 8);
            qf[mt][kc] = cv.v;
        }

    f32x4 oacc[4][4];
    float esum[4] = {0.f, 0.f, 0.f, 0.f};
#pragma unroll
    for (int mt = 0; mt < 4; ++mt)
#pragma unroll
        for (int x = 0; x < 4; ++x) oacc[mt][x] = (f32x4){0.f, 0.f, 0.f, 0.f};

    stageKV(0, 0);
    __syncthreads();
    int cur = 0;

    for (int t = 0; t < 8; ++t) {
        if (t < 7) stageKV(cur ^ 1, t + 1);

        // ---- QK^T: sacc[nt][mt]; lane holds q=lane&15, kv=16nt+4g+r ----
        f32x4 sacc[4][4];
#pragma unroll
        for (int nt = 0; nt < 4; ++nt)
#pragma unroll
            for (int mt = 0; mt < 4; ++mt) sacc[nt][mt] = (f32x4){0.f, 0.f, 0.f, 0.f};

#pragma unroll
        for (int kc = 0; kc < 2; ++kc) {
            bf16x8 kf[4];
#pragma unroll
            for (int nt = 0; nt < 4; ++nt) {
                const int kvl = nt * 16 + (lane & 15);
                int byte = kvl * 128 + kc * 64 + g * 16;
                byte ^= (kvl & 7) << 4;
                kf[nt] = *reinterpret_cast<const bf16x8*>(
                    reinterpret_cast<const char*>(&Kt[cur][0]) + byte);
            }
#pragma unroll
            for (int nt = 0; nt < 4; ++nt)
#pragma unroll
                for (int mt = 0; mt < 4; ++mt)
                    sacc[nt][mt] = __builtin_amdgcn_mfma_f32_16x16x32_bf16(
                        kf[nt], qf[mt][kc], sacc[nt][mt], 0, 0, 0);
        }

        // ---- transform in-register -> pa[c][mt] (A-frags for PV) ----
        // k-slot j of pa[c][mt] carries kv = 16*(2c+(j>>2)) + 4g + (j&3)
        bf16x8 pa[2][4];
#pragma unroll
        for (int c = 0; c < 2; ++c)
#pragma unroll
            for (int mt = 0; mt < 4; ++mt) {
                float w[8];
#pragma unroll
                for (int j = 0; j < 8; ++j) {
                    const float s  = sacc[2 * c + (j >> 2)][mt][j & 3];
                    const float a  = fminf(fabsf(s), 30.0f);
                    const float tt = __expf(a);
                    const float t2 = tt * tt;
                    const float u  = __builtin_amdgcn_sqrtf(fmaf(s, s, 0.01f));
                    const float dl = u - a;
                    const float ed = fmaf(dl, fmaf(dl, fmaf(dl, 0.16666667f, 0.5f), 1.0f), 1.0f);
                    const float eu = tt * ed;
                    esum[mt] += eu;
                    const float th = (t2 - 1.0f) * __builtin_amdgcn_rcpf(t2 + 1.0f);
                    w[j] = __builtin_copysignf(th * eu, s);
                }
                union { unsigned int u[4]; bf16x8 v; } pk;
#pragma unroll
                for (int p = 0; p < 4; ++p)
                    pk.u[p] = (__float_as_uint(w[2 * p + 1]) & 0xffff0000u) |
                              (__float_as_uint(w[2 * p]) >> 16);
                pa[c][mt] = pk.v;
            }

        // ---- PV with permuted B-frags from swizzled Vs ----
#pragma unroll
        for (int c = 0; c < 2; ++c) {
            bf16x8 vf[4];
#pragma unroll
            for (int dt = 0; dt < 4; ++dt) {
                const int d = dt * 16 + (lane & 15);
                const int swz = (d & 7) << 4;
                const int rowb = d * 128;
                uint2 lo = *reinterpret_cast<const uint2*>(
                    reinterpret_cast<const char*>(&Vs[cur][0]) +
                    (rowb + (((c * 32 + 4 * g) * 2) ^ swz)));
                uint2 hi = *reinterpret_cast<const uint2*>(
                    reinterpret_cast<const char*>(&Vs[cur][0]) +
                    (rowb + (((c * 32 + 16 + 4 * g) * 2) ^ swz)));
                union { unsigned int u[4]; bf16x8 v; } cvb;
                cvb.u[0] = lo.x; cvb.u[1] = lo.y;
                cvb.u[2] = hi.x; cvb.u[3] = hi.y;
                vf[dt] = cvb.v;
            }
#pragma unroll
            for (int mt = 0; mt < 4; ++mt)
#pragma unroll
                for (int dt = 0; dt < 4; ++dt)
                    oacc[mt][dt] = __builtin_amdgcn_mfma_f32_16x16x32_bf16(
                        pa[c][mt], vf[dt], oacc[mt][dt], 0, 0, 0);
        }

        __syncthreads();
        cur ^= 1;
    }

    // ---- epilogue: reduce esum, redistribute, normalize, residual ----
    float rden[4];
#pragma unroll
    for (int mt = 0; mt < 4; ++mt) {
        float e = esum[mt];
        e += __shfl_xor(e, 16);
        e += __shfl_xor(e, 32);
        rden[mt] = __builtin_amdgcn_rcpf(e);
    }
    float rr_[4][4];
#pragma unroll
    for (int mt = 0; mt < 4; ++mt)
#pragma unroll
        for (int r = 0; r < 4; ++r)
            rr_[mt][r] = __shfl(rden[mt], g * 4 + r);

#pragma unroll
    for (int mt = 0; mt < 4; ++mt)
#pragma unroll
        for (int dt = 0; dt < 4; ++dt)
#pragma unroll
            for (int r = 0; r < 4; ++r) {
                const int m = m0 + mt * 16 + g * 4 + r;
                const int d = dt * 16 + (lane & 15);
                const float qv = bf2f(Qb[(size_t)m * HDIM + d]);
                outq[((size_t)b * SEQ + m) * SIZE_D + h * HDIM + d] =
                    qv + oacc[mt][dt][r] * rr_[mt][r];
            }
}

// ---------------------------------------------------------------------------
// LN0: f32 in -> bf16 out (serves as GEMM-A and residual R)
// ---------------------------------------------------------------------------
__global__ __launch_bounds__(256) void ln0_bf16(const float* __restrict__ in,
                                                const float* __restrict__ w,
                                                const float* __restrict__ b,
                                                unsigned short* __restrict__ outb) {
    const int row = blockIdx.x;
    const int tid = threadIdx.x;
    const float2 x = *reinterpret_cast<const float2*>(&in[(size_t)row * SIZE_D + tid * 2]);

    float s  = x.x + x.y;
    float sq = x.x * x.x + x.y * x.y;
#pragma unroll
    for (int off = 32; off > 0; off >>= 1) {
        s  += __shfl_xor(s, off);
        sq += __shfl_xor(sq, off);
    }
    __shared__ float rs[4], rq[4];
    const int wv = tid >> 6;
    if ((tid & 63) == 0) { rs[wv] = s; rq[wv] = sq; }
    __syncthreads();
    s  = rs[0] + rs[1] + rs[2] + rs[3];
    sq = rq[0] + rq[1] + rq[2] + rq[3];

    const float mu  = s * (1.0f / SIZE_D);
    const float var = sq * (1.0f / SIZE_D) - mu * mu;
    const float rr  = rsqrtf(var + 1e-5f);

    const float2 wv2 = *reinterpret_cast<const float2*>(&w[tid * 2]);
    const float2 bv2 = *reinterpret_cast<const float2*>(&b[tid * 2]);
    ushort2 ob;
    ob.x = f2bf((x.x - mu) * rr * wv2.x + bv2.x);
    ob.y = f2bf((x.y - mu) * rr * wv2.y + bv2.y);
    *reinterpret_cast<ushort2*>(&outb[(size_t)row * SIZE_D + tid * 2]) = ob;
}

// ---------------------------------------------------------------------------
// Fused out-proj + ReLU + residual + LN1 -> d_out. BK=32, 2 blocks/CU.
// ---------------------------------------------------------------------------
__global__ __launch_bounds__(512, 2) void oproj_ln(const unsigned short* __restrict__ X,
                                                   const unsigned short* __restrict__ W,
                                                   const float* __restrict__ bo,
                                                   const float* __restrict__ g1,
                                                   const float* __restrict__ b1,
                                                   float* __restrict__ out) {
    __shared__ __align__(16) unsigned short Ad[2][64 * 32];
    __shared__ __align__(16) unsigned short Bd[2][512 * 32];
    __shared__ float red[64][8][2];
    __shared__ float stat[64][2];

    const int tid  = threadIdx.x;
    const int wv   = tid >> 6;
    const int lane = tid & 63;
    const int bm   = blockIdx.x * 64;

    auto stage = [&](int buf, int t) {
        const int k0 = t * 32;
        if (tid < 256) {
            const int o   = tid * 16;
            const int row = o >> 6;
            const int in  = (o & 63) ^ (((row >> 1) & 3) << 4);
            gload_lds16(X + (size_t)(bm + row) * SIZE_D + k0 + (in >> 1), &Ad[buf][o >> 1]);
        }
#pragma unroll
        for (int i = 0; i < 4; ++i) {
            const int o   = i * 8192 + tid * 16;
            const int row = o >> 6;
            const int in  = (o & 63) ^ (((row >> 1) & 3) << 4);
            gload_lds16(W + (size_t)row * SIZE_D + k0 + (in >> 1), &Bd[buf][o >> 1]);
        }
    };

    f32x4 acc[4][4];
#pragma unroll
    for (int mt = 0; mt < 4; ++mt)
#pragma unroll
        for (int nt = 0; nt < 4; ++nt) acc[mt][nt] = (f32x4){0.f, 0.f, 0.f, 0.f};

    stage(0, 0);
    __syncthreads();
    int cur = 0;

    for (int t = 0; t < 16; ++t) {
        if (t < 15) stage(cur ^ 1, t + 1);

        bf16x8 af[4], bfr[4];
#pragma unroll
        for (int mt = 0; mt < 4; ++mt) {
            const int r = mt * 16 + (lane & 15);
            int byte = r * 64 + (lane >> 4) * 16;
            byte ^= ((r >> 1) & 3) << 4;
            af[mt] = *reinterpret_cast<const bf16x8*>(
                reinterpret_cast<const char*>(&Ad[cur][0]) + byte);
        }
#pragma unroll
        for (int nt = 0; nt < 4; ++nt) {
            const int r = wv * 64 + nt * 16 + (lane & 15);
            int byte = r * 64 + (lane >> 4) * 16;
            byte ^= ((r >> 1) & 3) << 4;
            bfr[nt] = *reinterpret_cast<const bf16x8*>(
                reinterpret_cast<const char*>(&Bd[cur][0]) + byte);
        }
#pragma unroll
        for (int mt = 0; mt < 4; ++mt)
#pragma unroll
            for (int nt = 0; nt < 4; ++nt)
                acc[mt][nt] = __builtin_amdgcn_mfma_f32_16x16x32_bf16(
                    af[mt], bfr[nt], acc[mt][nt], 0, 0, 0);

        __syncthreads();
        cur ^= 1;
    }

#pragma unroll
    for (int nt = 0; nt < 4; ++nt) {
        const int n  = wv * 64 + nt * 16 + (lane & 15);
        const float bc = bo[n];
#pragma unroll
        for (int mt = 0; mt < 4; ++mt) {
            const int row0 = bm + mt * 16 + (lane >> 4) * 4;
#pragma unroll
            for (int r = 0; r < 4; ++r) {
                const float R = bf2f(X[(size_t)(row0 + r) * SIZE_D + n]);
                acc[mt][nt][r] = R + fmaxf(acc[mt][nt][r] + bc, 0.0f);
            }
        }
    }

    float ps[4][4], pq[4][4];
#pragma unroll
    for (int mt = 0; mt < 4; ++mt)
#pragma unroll
        for (int r = 0; r < 4; ++r) {
            float s = 0.f, q = 0.f;
#pragma unroll
            for (int nt = 0; nt < 4; ++nt) {
                const float v = acc[mt][nt][r];
                s += v; q += v * v;
            }
#pragma unroll
            for (int off = 1; off <= 8; off <<= 1) {
                s += __shfl_xor(s, off);
                q += __shfl_xor(q, off);
            }
            ps[mt][r] = s; pq[mt][r] = q;
        }
    {
        const int mtw = (lane & 15) >> 2, rw = lane & 3;
        const int rowL = mtw * 16 + (lane >> 4) * 4 + rw;
        red[rowL][wv][0] = ps[mtw][rw];
        red[rowL][wv][1] = pq[mtw][rw];
    }
    __syncthreads();
    if (tid < 64) {
        float s = 0.f, q = 0.f;
#pragma unroll
        for (int w8 = 0; w8 < 8; ++w8) { s += red[tid][w8][0]; q += red[tid][w8][1]; }
        const float mu  = s * (1.0f / SIZE_D);
        const float var = q * (1.0f / SIZE_D) - mu * mu;
        stat[tid][0] = mu;
        stat[tid][1] = rsqrtf(var + 1e-5f);
    }
    __syncthreads();

#pragma unroll
    for (int nt = 0; nt < 4; ++nt) {
        const int n = wv * 64 + nt * 16 + (lane & 15);
        const float g = g1[n], bb = b1[n];
#pragma unroll
        for (int mt = 0; mt < 4; ++mt) {
#pragma unroll
            for (int r = 0; r < 4; ++r) {
                const int rowL = mt * 16 + (lane >> 4) * 4 + r;
                const float y = (acc[mt][nt][r] - stat[rowL][0]) * stat[rowL][1];
                out[(size_t)(bm + rowL) * SIZE_D + n] = y * g + bb;
            }
        }
    }
}

// ---------------------------------------------------------------------------
extern "C" void kernel_launch(void* const* d_in, const int* in_sizes, int n_in,
                              void* d_out, int out_size, void* d_ws, size_t ws_size,
                              hipStream_t stream) {
    const float* query = (const float*)d_in[0];
    const float* keyv  = (const float*)d_in[1];
    const float* Wq    = (const float*)d_in[2];
    const float* bq    = (const float*)d_in[3];
    const float* Wk    = (const float*)d_in[4];
    const float* bk    = (const float*)d_in[5];
    const float* Wv    = (const float*)d_in[6];
    const float* bv    = (const float*)d_in[7];
    const float* Wo    = (const float*)d_in[8];
    const float* bo    = (const float*)d_in[9];
    const float* ln0w  = (const float*)d_in[10];
    const float* ln0b  = (const float*)d_in[11];
    const float* ln1w  = (const float*)d_in[12];
    const float* ln1b  = (const float*)d_in[13];
    float* out = (float*)d_out;

    // workspace layout:
    //   [ 0,32) qbuf f32 (attn output)
    //   [32,48) Qh bf16 head-major -> Xbf bf16 after ln0
    //   [48,64) Kh bf16 head-major (pre-scaled)
    //   [64,80) Vt bf16 transposed [b,h,d,kv]
    //   [80,82) Wbf: [Wq;Wk;Wv;Wo] bf16 contiguous
    char* ws = (char*)d_ws;
    float*          qbuf = (float*)ws;
    unsigned short* Qh   = (unsigned short*)(ws + ((size_t)32 << 20));
    unsigned short* Xbf  = Qh;
    unsigned short* Kh   = (unsigned short*)(ws + ((size_t)48 << 20));
    unsigned short* Vt   = (unsigned short*)(ws + ((size_t)64 << 20));
    unsigned short* Wbf  = (unsigned short*)(ws + ((size_t)80 << 20));
    unsigned short* WoB  = Wbf + 786432;

    cvt_w4<<<dim3(64, 4), 256, 0, stream>>>(Wq, Wk, Wv, Wo, Wbf);

    gemm_proj3<<<dim3(128, 12), 256, 0, stream>>>(query, keyv, Wbf, bq, bk, bv, Qh, Kh, Vt);

    attn_mfma<<<dim3(BATCH * HEADS, 2), 256, 0, stream>>>(Qh, Kh, Vt, qbuf);

    ln0_bf16<<<NROWS, 256, 0, stream>>>(qbuf, ln0w, ln0b, Xbf);

    oproj_ln<<<NROWS / 64, 512, 0, stream>>>(Xbf, WoB, bo, ln1w, ln1b, out);
}

// Round 15
// 159.757 us; speedup vs baseline: 1.0380x; 1.0062x over previous
//
#include <hip/hip_runtime.h>

#define SIZE_D 512
#define HEADS  8
#define HDIM   64
#define BATCH  32
#define SEQ    512
#define SCALE_F 0.125f   // 1/sqrt(64)
#define NROWS  (BATCH * SEQ)   // 16384

typedef __attribute__((ext_vector_type(8))) short bf16x8;
typedef __attribute__((ext_vector_type(4))) float f32x4;
typedef __attribute__((ext_vector_type(4))) unsigned int u32x4;

__device__ __forceinline__ unsigned short f2bf(float f) {
    union { float f; unsigned int u; } c{f};
    unsigned int x = c.u;
    x += 0x7fffu + ((x >> 16) & 1u);   // RNE
    return (unsigned short)(x >> 16);
}
__device__ __forceinline__ float bf2f(unsigned short u) {
    union { unsigned int i; float f; } c;
    c.i = (unsigned int)u << 16;
    return c.f;
}
__device__ __forceinline__ unsigned int pack2bf(float lo, float hi) {
    return ((__float_as_uint(hi) + 0x8000u) & 0xffff0000u) |
           ((__float_as_uint(lo) + 0x8000u) >> 16);
}
__device__ __forceinline__ void gload_lds16(const unsigned short* g, unsigned short* l) {
    __builtin_amdgcn_global_load_lds(
        (const __attribute__((address_space(1))) unsigned int*)g,
        (__attribute__((address_space(3))) unsigned int*)l, 16, 0, 0);
}

// counted-vmcnt barrier (T4): keep N newest VMEM ops in flight across the
// barrier; drain LDS ops. sched_barrier(0) fences reordering (rule 18).
#define KBAR8() do {                                                      \
    asm volatile("s_waitcnt vmcnt(8) lgkmcnt(0)" ::: "memory");           \
    __builtin_amdgcn_sched_barrier(0);                                    \
    __builtin_amdgcn_s_barrier();                                         \
    __builtin_amdgcn_sched_barrier(0);                                    \
} while (0)
#define KBAR0() do {                                                      \
    asm volatile("s_waitcnt vmcnt(0) lgkmcnt(0)" ::: "memory");           \
    __builtin_amdgcn_sched_barrier(0);                                    \
    __builtin_amdgcn_s_barrier();                                         \
    __builtin_amdgcn_sched_barrier(0);                                    \
} while (0)

// ---------------------------------------------------------------------------
// 4 weight matrices (512x512) -> contiguous bf16 [Wq;Wk;Wv;Wo]
// ---------------------------------------------------------------------------
__global__ __launch_bounds__(256) void cvt_w4(const float* __restrict__ w0,
                                              const float* __restrict__ w1,
                                              const float* __restrict__ w2,
                                              const float* __restrict__ w3,
                                              unsigned short* __restrict__ d) {
    const float* srcs[4] = {w0, w1, w2, w3};
    const float* s = srcs[blockIdx.y];
    unsigned short* dst = d + (size_t)blockIdx.y * (SIZE_D * SIZE_D);
    const int n = SIZE_D * SIZE_D;
    const int stride = gridDim.x * blockDim.x * 4;
    for (int i = (blockIdx.x * blockDim.x + threadIdx.x) * 4; i < n; i += stride) {
        const float4 v = *reinterpret_cast<const float4*>(s + i);
        ushort4 o;
        o.x = f2bf(v.x); o.y = f2bf(v.y); o.z = f2bf(v.z); o.w = f2bf(v.w);
        *reinterpret_cast<ushort4*>(dst + i) = o;
    }
}

// ---------------------------------------------------------------------------
// Merged projection GEMM, f32 A input, BK=64, 2-deep A pipeline, and
// COUNTED-VMCNT barriers (T4): per step, issue stageW(t+1) [4 gload_lds]
// THEN loadA(t+2) [8 vec loads]; top-of-step barrier waits vmcnt(8) —
// S_t complete, L_{t+1} stays in flight across the barrier. Last step
// drains. grid (128, 12): y 0..3 Q->Qh; 4..7 K->Kh (prescaled); 8..11 V->Vt.
// ---------------------------------------------------------------------------
__global__ __launch_bounds__(256, 2) void gemm_proj3(const float* __restrict__ query,
                                                     const float* __restrict__ keyv,
                                                     const unsigned short* __restrict__ Wall,
                                                     const float* __restrict__ bq,
                                                     const float* __restrict__ bk,
                                                     const float* __restrict__ bv,
                                                     unsigned short* __restrict__ Qh,
                                                     unsigned short* __restrict__ Kh,
                                                     unsigned short* __restrict__ Vt) {
    __shared__ __align__(16) unsigned short Ad[2][128 * 64];   // 16KB x2
    __shared__ __align__(16) unsigned short Bd[2][128 * 64];   // 16KB x2

    const int tid  = threadIdx.x;
    const int wv   = tid >> 6;
    const int lane = tid & 63;
    const int y    = blockIdx.y;
    const int bm   = blockIdx.x * 128;
    const int bn   = y * 128;
    const int wr   = wv >> 1;
    const int wc   = wv & 1;

    const float* A = (y < 4) ? query : keyv;

    float4 areg[2][4][2];   // [slot][i][half] — 2-deep pipeline

    auto loadA = [&](int t, int slot) {
        const int k0 = t * 64;
#pragma unroll
        for (int i = 0; i < 4; ++i) {
            const int o   = (wv * 32 + i * 8) * 128 + lane * 16;
            const int row = o >> 7;
            const int col = ((o & 127) ^ ((row & 7) << 4)) >> 1;
            const float* src = A + (size_t)(bm + row) * SIZE_D + k0 + col;
            areg[slot][i][0] = *reinterpret_cast<const float4*>(src);
            areg[slot][i][1] = *reinterpret_cast<const float4*>(src + 4);
        }
    };
    auto writeA = [&](int buf, int slot) {
#pragma unroll
        for (int i = 0; i < 4; ++i) {
            const int o = (wv * 32 + i * 8) * 128 + lane * 16;
            union { unsigned int u[4]; bf16x8 v; } pk;
            pk.u[0] = pack2bf(areg[slot][i][0].x, areg[slot][i][0].y);
            pk.u[1] = pack2bf(areg[slot][i][0].z, areg[slot][i][0].w);
            pk.u[2] = pack2bf(areg[slot][i][1].x, areg[slot][i][1].y);
            pk.u[3] = pack2bf(areg[slot][i][1].z, areg[slot][i][1].w);
            *reinterpret_cast<bf16x8*>(&Ad[buf][o >> 1]) = pk.v;
        }
    };
    auto stageW = [&](int buf, int t) {
        const int k0 = t * 64;
#pragma unroll
        for (int i = 0; i < 4; ++i) {
            const int o   = (wv * 32 + i * 8) * 128 + lane * 16;
            const int row = o >> 7;
            const int col = ((o & 127) ^ ((row & 7) << 4)) >> 1;
            gload_lds16(Wall + (size_t)(bn + row) * SIZE_D + k0 + col, &Bd[buf][o >> 1]);
        }
    };

    f32x4 acc[4][4];
#pragma unroll
    for (int mt = 0; mt < 4; ++mt)
#pragma unroll
        for (int nt = 0; nt < 4; ++nt) acc[mt][nt] = (f32x4){0.f, 0.f, 0.f, 0.f};

    // prologue: S_0 then L_0-consume, then L_1 in flight.
    loadA(0, 0);
    stageW(0, 0);          // S_0
    writeA(0, 0);          // compiler waits L_0 regs
    loadA(1, 1);           // L_1
    // FIFO now (unretired possible): [S_0(4), L_1(8)]

#pragma unroll
    for (int t = 0; t < 8; ++t) {
        const int cur = t & 1;
        // top-of-step barrier: S_t done; L_{t+1} stays in flight (t<7)
        if (t < 7) { KBAR8(); } else { KBAR0(); }

        if (t < 7) stageW(cur ^ 1, t + 1);     // S_{t+1}
        if (t < 6) loadA(t + 2, t & 1);        // L_{t+2}

        bf16x8 af[2][4], bfr[2][4];
#pragma unroll
        for (int kc = 0; kc < 2; ++kc) {
#pragma unroll
            for (int mt = 0; mt < 4; ++mt) {
                const int r = wr * 64 + mt * 16 + (lane & 15);
                int byte = r * 128 + kc * 64 + (lane >> 4) * 16;
                byte ^= (r & 7) << 4;
                af[kc][mt] = *reinterpret_cast<const bf16x8*>(
                    reinterpret_cast<const char*>(&Ad[cur][0]) + byte);
            }
#pragma unroll
            for (int nt = 0; nt < 4; ++nt) {
                const int r = wc * 64 + nt * 16 + (lane & 15);
                int byte = r * 128 + kc * 64 + (lane >> 4) * 16;
                byte ^= (r & 7) << 4;
                bfr[kc][nt] = *reinterpret_cast<const bf16x8*>(
                    reinterpret_cast<const char*>(&Bd[cur][0]) + byte);
            }
        }
#pragma unroll
        for (int kc = 0; kc < 2; ++kc)
#pragma unroll
            for (int mt = 0; mt < 4; ++mt)
#pragma unroll
                for (int nt = 0; nt < 4; ++nt)
                    acc[mt][nt] = __builtin_amdgcn_mfma_f32_16x16x32_bf16(
                        af[kc][mt], bfr[kc][nt], acc[mt][nt], 0, 0, 0);

        if (t < 7) writeA(cur ^ 1, (t + 1) & 1);   // compiler waits L_{t+1}
    }

    if (y < 8) {
        const float* bias = (y < 4) ? bq : bk;
        unsigned short* D = (y < 4) ? Qh : Kh;
        const int coff = (y < 4) ? 0 : 512;
#pragma unroll
        for (int nt = 0; nt < 4; ++nt) {
            const int colL = bn - coff + wc * 64 + nt * 16 + (lane & 15);
            const float bc = bias[colL];
            const int h = colL >> 6, dd = colL & 63;
#pragma unroll
            for (int mt = 0; mt < 4; ++mt) {
                const int row0 = bm + wr * 64 + mt * 16 + (lane >> 4) * 4;
#pragma unroll
                for (int r = 0; r < 4; ++r) {
                    const int row = row0 + r;
                    const int b_ = row >> 9, l = row & 511;
                    float z = acc[mt][nt][r] + bc;
                    if (y >= 4) z *= SCALE_F;
                    D[(((size_t)b_ * HEADS + h) * SEQ + l) * HDIM + dd] = f2bf(z);
                }
            }
        }
    } else {
#pragma unroll
        for (int nt = 0; nt < 4; ++nt) {
            const int c2 = bn - 1024 + wc * 64 + nt * 16 + (lane & 15);
            const float bc = bv[c2];
            const int hV = c2 >> 6, dV = c2 & 63;
#pragma unroll
            for (int mt = 0; mt < 4; ++mt) {
                const int row0 = bm + wr * 64 + mt * 16 + (lane >> 4) * 4;
                const int b_ = row0 >> 9, kv = row0 & 511;
                ushort4 pk;
                pk.x = f2bf(acc[mt][nt][0] + bc);
                pk.y = f2bf(acc[mt][nt][1] + bc);
                pk.z = f2bf(acc[mt][nt][2] + bc);
                pk.w = f2bf(acc[mt][nt][3] + bc);
                *reinterpret_cast<ushort4*>(
                    &Vt[(((size_t)b_ * HEADS + hV) * HDIM + dV) * SEQ + kv]) = pk;
            }
        }
    }
}

// ---------------------------------------------------------------------------
// MFMA attention — round-8/12 proven shell (unchanged).
// ---------------------------------------------------------------------------
__global__ __launch_bounds__(256, 2) void attn_mfma(const unsigned short* __restrict__ Qh,
                                                    const unsigned short* __restrict__ Kh,
                                                    const unsigned short* __restrict__ Vt,
                                                    float* __restrict__ outq) {
    __shared__ __align__(16) unsigned short Kt[2][64 * 64];   // [kv][d] swizzled
    __shared__ __align__(16) unsigned short Vs[2][64 * 64];   // [d][kv] swizzled

    const int tid  = threadIdx.x;
    const int wv   = tid >> 6;
    const int lane = tid & 63;
    const int bh   = blockIdx.x;
    const int b    = bh >> 3;
    const int h    = bh & 7;
    const int g    = lane >> 4;

    const unsigned short* Qb = Qh + (size_t)bh * (SEQ * HDIM);
    const unsigned short* Kb = Kh + (size_t)bh * (SEQ * HDIM);
    const unsigned short* Vb = Vt + (size_t)bh * (HDIM * SEQ);

    const int m0 = blockIdx.y * 256 + wv * 64;

    auto stageKV = [&](int buf, int t) {
        const int kv0 = t * 64;
#pragma unroll
        for (int i = 0; i < 2; ++i) {
            const int o   = i * 4096 + tid * 16;
            const int row = o >> 7;
            const int in  = (o & 127) ^ ((row & 7) << 4);
            gload_lds16(Kb + (size_t)(kv0 + row) * HDIM + (in >> 1), &Kt[buf][o >> 1]);
            gload_lds16(Vb + (size_t)row * SEQ + kv0 + (in >> 1), &Vs[buf][o >> 1]);
        }
    };

    bf16x8 qf[4][2];
#pragma unroll
    for (int mt = 0; mt < 4; ++mt)
#pragma unroll
        for (int kc = 0; kc < 2; ++kc) {
            const int m = m0 + mt * 16 + (lane & 15);
            union { u32x4 u; bf16x8 v; } cv;
            cv.u = *reinterpret_cast<const u32x4*>(
                Qb + (size_t)m * HDIM + kc * 32 + g * 8);
            qf[mt][kc] = cv.v;
        }

    f32x4 oacc[4][4];
    float esum[4] = {0.f, 0.f, 0.f, 0.f};
#pragma unroll
    for (int mt = 0; mt < 4; ++mt)
#pragma unroll
        for (int x = 0; x < 4; ++x) oacc[mt][x] = (f32x4){0.f, 0.f, 0.f, 0.f};

    stageKV(0, 0);
    __syncthreads();
    int cur = 0;

    for (int t = 0; t < 8; ++t) {
        if (t < 7) stageKV(cur ^ 1, t + 1);

        f32x4 sacc[4][4];
#pragma unroll
        for (int nt = 0; nt < 4; ++nt)
#pragma unroll
            for (int mt = 0; mt < 4; ++mt) sacc[nt][mt] = (f32x4){0.f, 0.f, 0.f, 0.f};

#pragma unroll
        for (int kc = 0; kc < 2; ++kc) {
            bf16x8 kf[4];
#pragma unroll
            for (int nt = 0; nt < 4; ++nt) {
                const int kvl = nt * 16 + (lane & 15);
                int byte = kvl * 128 + kc * 64 + g * 16;
                byte ^= (kvl & 7) << 4;
                kf[nt] = *reinterpret_cast<const bf16x8*>(
                    reinterpret_cast<const char*>(&Kt[cur][0]) + byte);
            }
#pragma unroll
            for (int nt = 0; nt < 4; ++nt)
#pragma unroll
                for (int mt = 0; mt < 4; ++mt)
                    sacc[nt][mt] = __builtin_amdgcn_mfma_f32_16x16x32_bf16(
                        kf[nt], qf[mt][kc], sacc[nt][mt], 0, 0, 0);
        }

        bf16x8 pa[2][4];
#pragma unroll
        for (int c = 0; c < 2; ++c)
#pragma unroll
            for (int mt = 0; mt < 4; ++mt) {
                float w[8];
#pragma unroll
                for (int j = 0; j < 8; ++j) {
                    const float s  = sacc[2 * c + (j >> 2)][mt][j & 3];
                    const float a  = fminf(fabsf(s), 30.0f);
                    const float tt = __expf(a);
                    const float t2 = tt * tt;
                    const float u  = __builtin_amdgcn_sqrtf(fmaf(s, s, 0.01f));
                    const float dl = u - a;
                    const float ed = fmaf(dl, fmaf(dl, fmaf(dl, 0.16666667f, 0.5f), 1.0f), 1.0f);
                    const float eu = tt * ed;
                    esum[mt] += eu;
                    const float th = (t2 - 1.0f) * __builtin_amdgcn_rcpf(t2 + 1.0f);
                    w[j] = __builtin_copysignf(th * eu, s);
                }
                union { unsigned int u[4]; bf16x8 v; } pk;
#pragma unroll
                for (int p = 0; p < 4; ++p)
                    pk.u[p] = (__float_as_uint(w[2 * p + 1]) & 0xffff0000u) |
                              (__float_as_uint(w[2 * p]) >> 16);
                pa[c][mt] = pk.v;
            }

#pragma unroll
        for (int c = 0; c < 2; ++c) {
            bf16x8 vf[4];
#pragma unroll
            for (int dt = 0; dt < 4; ++dt) {
                const int d = dt * 16 + (lane & 15);
                const int swz = (d & 7) << 4;
                const int rowb = d * 128;
                uint2 lo = *reinterpret_cast<const uint2*>(
                    reinterpret_cast<const char*>(&Vs[cur][0]) +
                    (rowb + (((c * 32 + 4 * g) * 2) ^ swz)));
                uint2 hi = *reinterpret_cast<const uint2*>(
                    reinterpret_cast<const char*>(&Vs[cur][0]) +
                    (rowb + (((c * 32 + 16 + 4 * g) * 2) ^ swz)));
                union { unsigned int u[4]; bf16x8 v; } cvb;
                cvb.u[0] = lo.x; cvb.u[1] = lo.y;
                cvb.u[2] = hi.x; cvb.u[3] = hi.y;
                vf[dt] = cvb.v;
            }
#pragma unroll
            for (int mt = 0; mt < 4; ++mt)
#pragma unroll
                for (int dt = 0; dt < 4; ++dt)
                    oacc[mt][dt] = __builtin_amdgcn_mfma_f32_16x16x32_bf16(
                        pa[c][mt], vf[dt], oacc[mt][dt], 0, 0, 0);
        }

        __syncthreads();
        cur ^= 1;
    }

    float rden[4];
#pragma unroll
    for (int mt = 0; mt < 4; ++mt) {
        float e = esum[mt];
        e += __shfl_xor(e, 16);
        e += __shfl_xor(e, 32);
        rden[mt] = __builtin_amdgcn_rcpf(e);
    }
    float rr_[4][4];
#pragma unroll
    for (int mt = 0; mt < 4; ++mt)
#pragma unroll
        for (int r = 0; r < 4; ++r)
            rr_[mt][r] = __shfl(rden[mt], g * 4 + r);

#pragma unroll
    for (int mt = 0; mt < 4; ++mt)
#pragma unroll
        for (int dt = 0; dt < 4; ++dt)
#pragma unroll
            for (int r = 0; r < 4; ++r) {
                const int m = m0 + mt * 16 + g * 4 + r;
                const int d = dt * 16 + (lane & 15);
                const float qv = bf2f(Qb[(size_t)m * HDIM + d]);
                outq[((size_t)b * SEQ + m) * SIZE_D + h * HDIM + d] =
                    qv + oacc[mt][dt][r] * rr_[mt][r];
            }
}

// ---------------------------------------------------------------------------
// LN0: f32 in -> bf16 out (serves as GEMM-A and residual R)
// ---------------------------------------------------------------------------
__global__ __launch_bounds__(256) void ln0_bf16(const float* __restrict__ in,
                                                const float* __restrict__ w,
                                                const float* __restrict__ b,
                                                unsigned short* __restrict__ outb) {
    const int row = blockIdx.x;
    const int tid = threadIdx.x;
    const float2 x = *reinterpret_cast<const float2*>(&in[(size_t)row * SIZE_D + tid * 2]);

    float s  = x.x + x.y;
    float sq = x.x * x.x + x.y * x.y;
#pragma unroll
    for (int off = 32; off > 0; off >>= 1) {
        s  += __shfl_xor(s, off);
        sq += __shfl_xor(sq, off);
    }
    __shared__ float rs[4], rq[4];
    const int wv = tid >> 6;
    if ((tid & 63) == 0) { rs[wv] = s; rq[wv] = sq; }
    __syncthreads();
    s  = rs[0] + rs[1] + rs[2] + rs[3];
    sq = rq[0] + rq[1] + rq[2] + rq[3];

    const float mu  = s * (1.0f / SIZE_D);
    const float var = sq * (1.0f / SIZE_D) - mu * mu;
    const float rr  = rsqrtf(var + 1e-5f);

    const float2 wv2 = *reinterpret_cast<const float2*>(&w[tid * 2]);
    const float2 bv2 = *reinterpret_cast<const float2*>(&b[tid * 2]);
    ushort2 ob;
    ob.x = f2bf((x.x - mu) * rr * wv2.x + bv2.x);
    ob.y = f2bf((x.y - mu) * rr * wv2.y + bv2.y);
    *reinterpret_cast<ushort2*>(&outb[(size_t)row * SIZE_D + tid * 2]) = ob;
}

// ---------------------------------------------------------------------------
// Fused out-proj + ReLU + residual + LN1 -> d_out. BK=32, 2 blocks/CU.
// ---------------------------------------------------------------------------
__global__ __launch_bounds__(512, 2) void oproj_ln(const unsigned short* __restrict__ X,
                                                   const unsigned short* __restrict__ W,
                                                   const float* __restrict__ bo,
                                                   const float* __restrict__ g1,
                                                   const float* __restrict__ b1,
                                                   float* __restrict__ out) {
    __shared__ __align__(16) unsigned short Ad[2][64 * 32];
    __shared__ __align__(16) unsigned short Bd[2][512 * 32];
    __shared__ float red[64][8][2];
    __shared__ float stat[64][2];

    const int tid  = threadIdx.x;
    const int wv   = tid >> 6;
    const int lane = tid & 63;
    const int bm   = blockIdx.x * 64;

    auto stage = [&](int buf, int t) {
        const int k0 = t * 32;
        if (tid < 256) {
            const int o   = tid * 16;
            const int row = o >> 6;
            const int in  = (o & 63) ^ (((row >> 1) & 3) << 4);
            gload_lds16(X + (size_t)(bm + row) * SIZE_D + k0 + (in >> 1), &Ad[buf][o >> 1]);
        }
#pragma unroll
        for (int i = 0; i < 4; ++i) {
            const int o   = i * 8192 + tid * 16;
            const int row = o >> 6;
            const int in  = (o & 63) ^ (((row >> 1) & 3) << 4);
            gload_lds16(W + (size_t)row * SIZE_D + k0 + (in >> 1), &Bd[buf][o >> 1]);
        }
    };

    f32x4 acc[4][4];
#pragma unroll
    for (int mt = 0; mt < 4; ++mt)
#pragma unroll
        for (int nt = 0; nt < 4; ++nt) acc[mt][nt] = (f32x4){0.f, 0.f, 0.f, 0.f};

    stage(0, 0);
    __syncthreads();
    int cur = 0;

    for (int t = 0; t < 16; ++t) {
        if (t < 15) stage(cur ^ 1, t + 1);

        bf16x8 af[4], bfr[4];
#pragma unroll
        for (int mt = 0; mt < 4; ++mt) {
            const int r = mt * 16 + (lane & 15);
            int byte = r * 64 + (lane >> 4) * 16;
            byte ^= ((r >> 1) & 3) << 4;
            af[mt] = *reinterpret_cast<const bf16x8*>(
                reinterpret_cast<const char*>(&Ad[cur][0]) + byte);
        }
#pragma unroll
        for (int nt = 0; nt < 4; ++nt) {
            const int r = wv * 64 + nt * 16 + (lane & 15);
            int byte = r * 64 + (lane >> 4) * 16;
            byte ^= ((r >> 1) & 3) << 4;
            bfr[nt] = *reinterpret_cast<const bf16x8*>(
                reinterpret_cast<const char*>(&Bd[cur][0]) + byte);
        }
#pragma unroll
        for (int mt = 0; mt < 4; ++mt)
#pragma unroll
            for (int nt = 0; nt < 4; ++nt)
                acc[mt][nt] = __builtin_amdgcn_mfma_f32_16x16x32_bf16(
                    af[mt], bfr[nt], acc[mt][nt], 0, 0, 0);

        __syncthreads();
        cur ^= 1;
    }

#pragma unroll
    for (int nt = 0; nt < 4; ++nt) {
        const int n  = wv * 64 + nt * 16 + (lane & 15);
        const float bc = bo[n];
#pragma unroll
        for (int mt = 0; mt < 4; ++mt) {
            const int row0 = bm + mt * 16 + (lane >> 4) * 4;
#pragma unroll
            for (int r = 0; r < 4; ++r) {
                const float R = bf2f(X[(size_t)(row0 + r) * SIZE_D + n]);
                acc[mt][nt][r] = R + fmaxf(acc[mt][nt][r] + bc, 0.0f);
            }
        }
    }

    float ps[4][4], pq[4][4];
#pragma unroll
    for (int mt = 0; mt < 4; ++mt)
#pragma unroll
        for (int r = 0; r < 4; ++r) {
            float s = 0.f, q = 0.f;
#pragma unroll
            for (int nt = 0; nt < 4; ++nt) {
                const float v = acc[mt][nt][r];
                s += v; q += v * v;
            }
#pragma unroll
            for (int off = 1; off <= 8; off <<= 1) {
                s += __shfl_xor(s, off);
                q += __shfl_xor(q, off);
            }
            ps[mt][r] = s; pq[mt][r] = q;
        }
    {
        const int mtw = (lane & 15) >> 2, rw = lane & 3;
        const int rowL = mtw * 16 + (lane >> 4) * 4 + rw;
        red[rowL][wv][0] = ps[mtw][rw];
        red[rowL][wv][1] = pq[mtw][rw];
    }
    __syncthreads();
    if (tid < 64) {
        float s = 0.f, q = 0.f;
#pragma unroll
        for (int w8 = 0; w8 < 8; ++w8) { s += red[tid][w8][0]; q += red[tid][w8][1]; }
        const float mu  = s * (1.0f / SIZE_D);
        const float var = q * (1.0f / SIZE_D) - mu * mu;
        stat[tid][0] = mu;
        stat[tid][1] = rsqrtf(var + 1e-5f);
    }
    __syncthreads();

#pragma unroll
    for (int nt = 0; nt < 4; ++nt) {
        const int n = wv * 64 + nt * 16 + (lane & 15);
        const float g = g1[n], bb = b1[n];
#pragma unroll
        for (int mt = 0; mt < 4; ++mt) {
#pragma unroll
            for (int r = 0; r < 4; ++r) {
                const int rowL = mt * 16 + (lane >> 4) * 4 + r;
                const float y = (acc[mt][nt][r] - stat[rowL][0]) * stat[rowL][1];
                out[(size_t)(bm + rowL) * SIZE_D + n] = y * g + bb;
            }
        }
    }
}

// ---------------------------------------------------------------------------
extern "C" void kernel_launch(void* const* d_in, const int* in_sizes, int n_in,
                              void* d_out, int out_size, void* d_ws, size_t ws_size,
                              hipStream_t stream) {
    const float* query = (const float*)d_in[0];
    const float* keyv  = (const float*)d_in[1];
    const float* Wq    = (const float*)d_in[2];
    const float* bq    = (const float*)d_in[3];
    const float* Wk    = (const float*)d_in[4];
    const float* bk    = (const float*)d_in[5];
    const float* Wv    = (const float*)d_in[6];
    const float* bv    = (const float*)d_in[7];
    const float* Wo    = (const float*)d_in[8];
    const float* bo    = (const float*)d_in[9];
    const float* ln0w  = (const float*)d_in[10];
    const float* ln0b  = (const float*)d_in[11];
    const float* ln1w  = (const float*)d_in[12];
    const float* ln1b  = (const float*)d_in[13];
    float* out = (float*)d_out;

    // workspace layout:
    //   [ 0,32) qbuf f32 (attn output)
    //   [32,48) Qh bf16 head-major -> Xbf bf16 after ln0
    //   [48,64) Kh bf16 head-major (pre-scaled)
    //   [64,80) Vt bf16 transposed [b,h,d,kv]
    //   [80,82) Wbf: [Wq;Wk;Wv;Wo] bf16 contiguous
    char* ws = (char*)d_ws;
    float*          qbuf = (float*)ws;
    unsigned short* Qh   = (unsigned short*)(ws + ((size_t)32 << 20));
    unsigned short* Xbf  = Qh;
    unsigned short* Kh   = (unsigned short*)(ws + ((size_t)48 << 20));
    unsigned short* Vt   = (unsigned short*)(ws + ((size_t)64 << 20));
    unsigned short* Wbf  = (unsigned short*)(ws + ((size_t)80 << 20));
    unsigned short* WoB  = Wbf + 786432;

    cvt_w4<<<dim3(64, 4), 256, 0, stream>>>(Wq, Wk, Wv, Wo, Wbf);

    gemm_proj3<<<dim3(128, 12), 256, 0, stream>>>(query, keyv, Wbf, bq, bk, bv, Qh, Kh, Vt);

    attn_mfma<<<dim3(BATCH * HEADS, 2), 256, 0, stream>>>(Qh, Kh, Vt, qbuf);

    ln0_bf16<<<NROWS, 256, 0, stream>>>(qbuf, ln0w, ln0b, Xbf);

    oproj_ln<<<NROWS / 64, 512, 0, stream>>>(Xbf, WoB, bo, ln1w, ln1b, out);
}

// Round 16
// 156.483 us; speedup vs baseline: 1.0597x; 1.0209x over previous
//
#include <hip/hip_runtime.h>

#define SIZE_D 512
#define HEADS  8
#define HDIM   64
#define BATCH  32
#define SEQ    512
#define SCALE_F 0.125f   // 1/sqrt(64)
#define NROWS  (BATCH * SEQ)   // 16384

typedef __attribute__((ext_vector_type(8))) short bf16x8;
typedef __attribute__((ext_vector_type(4))) float f32x4;
typedef __attribute__((ext_vector_type(4))) unsigned int u32x4;

__device__ __forceinline__ unsigned short f2bf(float f) {
    union { float f; unsigned int u; } c{f};
    unsigned int x = c.u;
    x += 0x7fffu + ((x >> 16) & 1u);   // RNE
    return (unsigned short)(x >> 16);
}
__device__ __forceinline__ float bf2f(unsigned short u) {
    union { unsigned int i; float f; } c;
    c.i = (unsigned int)u << 16;
    return c.f;
}
__device__ __forceinline__ unsigned int pack2bf(float lo, float hi) {
    return ((__float_as_uint(hi) + 0x8000u) & 0xffff0000u) |
           ((__float_as_uint(lo) + 0x8000u) >> 16);
}
__device__ __forceinline__ void gload_lds16(const unsigned short* g, unsigned short* l) {
    __builtin_amdgcn_global_load_lds(
        (const __attribute__((address_space(1))) unsigned int*)g,
        (__attribute__((address_space(3))) unsigned int*)l, 16, 0, 0);
}

// counted-vmcnt barrier (T4), r15-proven in gemm_proj3
#define KBAR8() do {                                                      \
    asm volatile("s_waitcnt vmcnt(8) lgkmcnt(0)" ::: "memory");           \
    __builtin_amdgcn_sched_barrier(0);                                    \
    __builtin_amdgcn_s_barrier();                                         \
    __builtin_amdgcn_sched_barrier(0);                                    \
} while (0)
#define KBAR0() do {                                                      \
    asm volatile("s_waitcnt vmcnt(0) lgkmcnt(0)" ::: "memory");           \
    __builtin_amdgcn_sched_barrier(0);                                    \
    __builtin_amdgcn_s_barrier();                                         \
    __builtin_amdgcn_sched_barrier(0);                                    \
} while (0)

// ---------------------------------------------------------------------------
// 4 weight matrices (512x512) -> contiguous bf16 [Wq;Wk;Wv;Wo]
// ---------------------------------------------------------------------------
__global__ __launch_bounds__(256) void cvt_w4(const float* __restrict__ w0,
                                              const float* __restrict__ w1,
                                              const float* __restrict__ w2,
                                              const float* __restrict__ w3,
                                              unsigned short* __restrict__ d) {
    const float* srcs[4] = {w0, w1, w2, w3};
    const float* s = srcs[blockIdx.y];
    unsigned short* dst = d + (size_t)blockIdx.y * (SIZE_D * SIZE_D);
    const int n = SIZE_D * SIZE_D;
    const int stride = gridDim.x * blockDim.x * 4;
    for (int i = (blockIdx.x * blockDim.x + threadIdx.x) * 4; i < n; i += stride) {
        const float4 v = *reinterpret_cast<const float4*>(s + i);
        ushort4 o;
        o.x = f2bf(v.x); o.y = f2bf(v.y); o.z = f2bf(v.z); o.w = f2bf(v.w);
        *reinterpret_cast<ushort4*>(dst + i) = o;
    }
}

// ---------------------------------------------------------------------------
// Merged projection GEMM (r15-proven): f32 A, BK=64, 2-deep A pipeline,
// counted-vmcnt barriers. grid (128,12): y 0..3 Q->Qh; 4..7 K->Kh
// (prescaled); 8..11 V->Vt.
// ---------------------------------------------------------------------------
__global__ __launch_bounds__(256, 2) void gemm_proj3(const float* __restrict__ query,
                                                     const float* __restrict__ keyv,
                                                     const unsigned short* __restrict__ Wall,
                                                     const float* __restrict__ bq,
                                                     const float* __restrict__ bk,
                                                     const float* __restrict__ bv,
                                                     unsigned short* __restrict__ Qh,
                                                     unsigned short* __restrict__ Kh,
                                                     unsigned short* __restrict__ Vt) {
    __shared__ __align__(16) unsigned short Ad[2][128 * 64];
    __shared__ __align__(16) unsigned short Bd[2][128 * 64];

    const int tid  = threadIdx.x;
    const int wv   = tid >> 6;
    const int lane = tid & 63;
    const int y    = blockIdx.y;
    const int bm   = blockIdx.x * 128;
    const int bn   = y * 128;
    const int wr   = wv >> 1;
    const int wc   = wv & 1;

    const float* A = (y < 4) ? query : keyv;

    float4 areg[2][4][2];

    auto loadA = [&](int t, int slot) {
        const int k0 = t * 64;
#pragma unroll
        for (int i = 0; i < 4; ++i) {
            const int o   = (wv * 32 + i * 8) * 128 + lane * 16;
            const int row = o >> 7;
            const int col = ((o & 127) ^ ((row & 7) << 4)) >> 1;
            const float* src = A + (size_t)(bm + row) * SIZE_D + k0 + col;
            areg[slot][i][0] = *reinterpret_cast<const float4*>(src);
            areg[slot][i][1] = *reinterpret_cast<const float4*>(src + 4);
        }
    };
    auto writeA = [&](int buf, int slot) {
#pragma unroll
        for (int i = 0; i < 4; ++i) {
            const int o = (wv * 32 + i * 8) * 128 + lane * 16;
            union { unsigned int u[4]; bf16x8 v; } pk;
            pk.u[0] = pack2bf(areg[slot][i][0].x, areg[slot][i][0].y);
            pk.u[1] = pack2bf(areg[slot][i][0].z, areg[slot][i][0].w);
            pk.u[2] = pack2bf(areg[slot][i][1].x, areg[slot][i][1].y);
            pk.u[3] = pack2bf(areg[slot][i][1].z, areg[slot][i][1].w);
            *reinterpret_cast<bf16x8*>(&Ad[buf][o >> 1]) = pk.v;
        }
    };
    auto stageW = [&](int buf, int t) {
        const int k0 = t * 64;
#pragma unroll
        for (int i = 0; i < 4; ++i) {
            const int o   = (wv * 32 + i * 8) * 128 + lane * 16;
            const int row = o >> 7;
            const int col = ((o & 127) ^ ((row & 7) << 4)) >> 1;
            gload_lds16(Wall + (size_t)(bn + row) * SIZE_D + k0 + col, &Bd[buf][o >> 1]);
        }
    };

    f32x4 acc[4][4];
#pragma unroll
    for (int mt = 0; mt < 4; ++mt)
#pragma unroll
        for (int nt = 0; nt < 4; ++nt) acc[mt][nt] = (f32x4){0.f, 0.f, 0.f, 0.f};

    loadA(0, 0);
    stageW(0, 0);
    writeA(0, 0);
    loadA(1, 1);

#pragma unroll
    for (int t = 0; t < 8; ++t) {
        const int cur = t & 1;
        if (t < 7) { KBAR8(); } else { KBAR0(); }

        if (t < 7) stageW(cur ^ 1, t + 1);
        if (t < 6) loadA(t + 2, t & 1);

        bf16x8 af[2][4], bfr[2][4];
#pragma unroll
        for (int kc = 0; kc < 2; ++kc) {
#pragma unroll
            for (int mt = 0; mt < 4; ++mt) {
                const int r = wr * 64 + mt * 16 + (lane & 15);
                int byte = r * 128 + kc * 64 + (lane >> 4) * 16;
                byte ^= (r & 7) << 4;
                af[kc][mt] = *reinterpret_cast<const bf16x8*>(
                    reinterpret_cast<const char*>(&Ad[cur][0]) + byte);
            }
#pragma unroll
            for (int nt = 0; nt < 4; ++nt) {
                const int r = wc * 64 + nt * 16 + (lane & 15);
                int byte = r * 128 + kc * 64 + (lane >> 4) * 16;
                byte ^= (r & 7) << 4;
                bfr[kc][nt] = *reinterpret_cast<const bf16x8*>(
                    reinterpret_cast<const char*>(&Bd[cur][0]) + byte);
            }
        }
#pragma unroll
        for (int kc = 0; kc < 2; ++kc)
#pragma unroll
            for (int mt = 0; mt < 4; ++mt)
#pragma unroll
                for (int nt = 0; nt < 4; ++nt)
                    acc[mt][nt] = __builtin_amdgcn_mfma_f32_16x16x32_bf16(
                        af[kc][mt], bfr[kc][nt], acc[mt][nt], 0, 0, 0);

        if (t < 7) writeA(cur ^ 1, (t + 1) & 1);
    }

    if (y < 8) {
        const float* bias = (y < 4) ? bq : bk;
        unsigned short* D = (y < 4) ? Qh : Kh;
        const int coff = (y < 4) ? 0 : 512;
#pragma unroll
        for (int nt = 0; nt < 4; ++nt) {
            const int colL = bn - coff + wc * 64 + nt * 16 + (lane & 15);
            const float bc = bias[colL];
            const int h = colL >> 6, dd = colL & 63;
#pragma unroll
            for (int mt = 0; mt < 4; ++mt) {
                const int row0 = bm + wr * 64 + mt * 16 + (lane >> 4) * 4;
#pragma unroll
                for (int r = 0; r < 4; ++r) {
                    const int row = row0 + r;
                    const int b_ = row >> 9, l = row & 511;
                    float z = acc[mt][nt][r] + bc;
                    if (y >= 4) z *= SCALE_F;
                    D[(((size_t)b_ * HEADS + h) * SEQ + l) * HDIM + dd] = f2bf(z);
                }
            }
        }
    } else {
#pragma unroll
        for (int nt = 0; nt < 4; ++nt) {
            const int c2 = bn - 1024 + wc * 64 + nt * 16 + (lane & 15);
            const float bc = bv[c2];
            const int hV = c2 >> 6, dV = c2 & 63;
#pragma unroll
            for (int mt = 0; mt < 4; ++mt) {
                const int row0 = bm + wr * 64 + mt * 16 + (lane >> 4) * 4;
                const int b_ = row0 >> 9, kv = row0 & 511;
                ushort4 pk;
                pk.x = f2bf(acc[mt][nt][0] + bc);
                pk.y = f2bf(acc[mt][nt][1] + bc);
                pk.z = f2bf(acc[mt][nt][2] + bc);
                pk.w = f2bf(acc[mt][nt][3] + bc);
                *reinterpret_cast<ushort4*>(
                    &Vt[(((size_t)b_ * HEADS + hV) * HDIM + dV) * SEQ + kv]) = pk;
            }
        }
    }
}

// ---------------------------------------------------------------------------
// MFMA attention — round-8/12 proven shell + (a) bf16 output with residual,
// (b) th = fma(-2, rcp(t2+1), 1), (c) s_setprio(1) around MFMA clusters (T5).
// ---------------------------------------------------------------------------
__global__ __launch_bounds__(256, 2) void attn_mfma(const unsigned short* __restrict__ Qh,
                                                    const unsigned short* __restrict__ Kh,
                                                    const unsigned short* __restrict__ Vt,
                                                    unsigned short* __restrict__ outb) {
    __shared__ __align__(16) unsigned short Kt[2][64 * 64];   // [kv][d] swizzled
    __shared__ __align__(16) unsigned short Vs[2][64 * 64];   // [d][kv] swizzled

    const int tid  = threadIdx.x;
    const int wv   = tid >> 6;
    const int lane = tid & 63;
    const int bh   = blockIdx.x;
    const int b    = bh >> 3;
    const int h    = bh & 7;
    const int g    = lane >> 4;

    const unsigned short* Qb = Qh + (size_t)bh * (SEQ * HDIM);
    const unsigned short* Kb = Kh + (size_t)bh * (SEQ * HDIM);
    const unsigned short* Vb = Vt + (size_t)bh * (HDIM * SEQ);

    const int m0 = blockIdx.y * 256 + wv * 64;

    auto stageKV = [&](int buf, int t) {
        const int kv0 = t * 64;
#pragma unroll
        for (int i = 0; i < 2; ++i) {
            const int o   = i * 4096 + tid * 16;
            const int row = o >> 7;
            const int in  = (o & 127) ^ ((row & 7) << 4);
            gload_lds16(Kb + (size_t)(kv0 + row) * HDIM + (in >> 1), &Kt[buf][o >> 1]);
            gload_lds16(Vb + (size_t)row * SEQ + kv0 + (in >> 1), &Vs[buf][o >> 1]);
        }
    };

    bf16x8 qf[4][2];
#pragma unroll
    for (int mt = 0; mt < 4; ++mt)
#pragma unroll
        for (int kc = 0; kc < 2; ++kc) {
            const int m = m0 + mt * 16 + (lane & 15);
            union { u32x4 u; bf16x8 v; } cv;
            cv.u = *reinterpret_cast<const u32x4*>(
                Qb + (size_t)m * HDIM + kc * 32 + g * 8);
            qf[mt][kc] = cv.v;
        }

    f32x4 oacc[4][4];
    float esum[4] = {0.f, 0.f, 0.f, 0.f};
#pragma unroll
    for (int mt = 0; mt < 4; ++mt)
#pragma unroll
        for (int x = 0; x < 4; ++x) oacc[mt][x] = (f32x4){0.f, 0.f, 0.f, 0.f};

    stageKV(0, 0);
    __syncthreads();
    int cur = 0;

    for (int t = 0; t < 8; ++t) {
        if (t < 7) stageKV(cur ^ 1, t + 1);

        f32x4 sacc[4][4];
#pragma unroll
        for (int nt = 0; nt < 4; ++nt)
#pragma unroll
            for (int mt = 0; mt < 4; ++mt) sacc[nt][mt] = (f32x4){0.f, 0.f, 0.f, 0.f};

#pragma unroll
        for (int kc = 0; kc < 2; ++kc) {
            bf16x8 kf[4];
#pragma unroll
            for (int nt = 0; nt < 4; ++nt) {
                const int kvl = nt * 16 + (lane & 15);
                int byte = kvl * 128 + kc * 64 + g * 16;
                byte ^= (kvl & 7) << 4;
                kf[nt] = *reinterpret_cast<const bf16x8*>(
                    reinterpret_cast<const char*>(&Kt[cur][0]) + byte);
            }
            __builtin_amdgcn_s_setprio(1);
#pragma unroll
            for (int nt = 0; nt < 4; ++nt)
#pragma unroll
                for (int mt = 0; mt < 4; ++mt)
                    sacc[nt][mt] = __builtin_amdgcn_mfma_f32_16x16x32_bf16(
                        kf[nt], qf[mt][kc], sacc[nt][mt], 0, 0, 0);
            __builtin_amdgcn_s_setprio(0);
        }

        bf16x8 pa[2][4];
#pragma unroll
        for (int c = 0; c < 2; ++c)
#pragma unroll
            for (int mt = 0; mt < 4; ++mt) {
                float w[8];
#pragma unroll
                for (int j = 0; j < 8; ++j) {
                    const float s  = sacc[2 * c + (j >> 2)][mt][j & 3];
                    const float a  = fminf(fabsf(s), 30.0f);
                    const float tt = __expf(a);
                    const float t2 = tt * tt;
                    const float u  = __builtin_amdgcn_sqrtf(fmaf(s, s, 0.01f));
                    const float dl = u - a;
                    const float ed = fmaf(dl, fmaf(dl, fmaf(dl, 0.16666667f, 0.5f), 1.0f), 1.0f);
                    const float eu = tt * ed;
                    esum[mt] += eu;
                    const float th = fmaf(-2.0f, __builtin_amdgcn_rcpf(t2 + 1.0f), 1.0f);
                    w[j] = __builtin_copysignf(th * eu, s);
                }
                union { unsigned int u[4]; bf16x8 v; } pk;
#pragma unroll
                for (int p = 0; p < 4; ++p)
                    pk.u[p] = (__float_as_uint(w[2 * p + 1]) & 0xffff0000u) |
                              (__float_as_uint(w[2 * p]) >> 16);
                pa[c][mt] = pk.v;
            }

#pragma unroll
        for (int c = 0; c < 2; ++c) {
            bf16x8 vf[4];
#pragma unroll
            for (int dt = 0; dt < 4; ++dt) {
                const int d = dt * 16 + (lane & 15);
                const int swz = (d & 7) << 4;
                const int rowb = d * 128;
                uint2 lo = *reinterpret_cast<const uint2*>(
                    reinterpret_cast<const char*>(&Vs[cur][0]) +
                    (rowb + (((c * 32 + 4 * g) * 2) ^ swz)));
                uint2 hi = *reinterpret_cast<const uint2*>(
                    reinterpret_cast<const char*>(&Vs[cur][0]) +
                    (rowb + (((c * 32 + 16 + 4 * g) * 2) ^ swz)));
                union { unsigned int u[4]; bf16x8 v; } cvb;
                cvb.u[0] = lo.x; cvb.u[1] = lo.y;
                cvb.u[2] = hi.x; cvb.u[3] = hi.y;
                vf[dt] = cvb.v;
            }
            __builtin_amdgcn_s_setprio(1);
#pragma unroll
            for (int mt = 0; mt < 4; ++mt)
#pragma unroll
                for (int dt = 0; dt < 4; ++dt)
                    oacc[mt][dt] = __builtin_amdgcn_mfma_f32_16x16x32_bf16(
                        pa[c][mt], vf[dt], oacc[mt][dt], 0, 0, 0);
            __builtin_amdgcn_s_setprio(0);
        }

        __syncthreads();
        cur ^= 1;
    }

    float rden[4];
#pragma unroll
    for (int mt = 0; mt < 4; ++mt) {
        float e = esum[mt];
        e += __shfl_xor(e, 16);
        e += __shfl_xor(e, 32);
        rden[mt] = __builtin_amdgcn_rcpf(e);
    }
    float rr_[4][4];
#pragma unroll
    for (int mt = 0; mt < 4; ++mt)
#pragma unroll
        for (int r = 0; r < 4; ++r)
            rr_[mt][r] = __shfl(rden[mt], g * 4 + r);

    // bf16 output with residual (halves write traffic)
#pragma unroll
    for (int mt = 0; mt < 4; ++mt)
#pragma unroll
        for (int dt = 0; dt < 4; ++dt)
#pragma unroll
            for (int r = 0; r < 4; ++r) {
                const int m = m0 + mt * 16 + g * 4 + r;
                const int d = dt * 16 + (lane & 15);
                const float qv = bf2f(Qb[(size_t)m * HDIM + d]);
                outb[((size_t)b * SEQ + m) * SIZE_D + h * HDIM + d] =
                    f2bf(qv + oacc[mt][dt][r] * rr_[mt][r]);
            }
}

// ---------------------------------------------------------------------------
// LN0: bf16 in -> bf16 out (serves as GEMM-A and residual R)
// ---------------------------------------------------------------------------
__global__ __launch_bounds__(256) void ln0_bf16(const unsigned short* __restrict__ in,
                                                const float* __restrict__ w,
                                                const float* __restrict__ b,
                                                unsigned short* __restrict__ outb) {
    const int row = blockIdx.x;
    const int tid = threadIdx.x;
    const ushort2 xb = *reinterpret_cast<const ushort2*>(&in[(size_t)row * SIZE_D + tid * 2]);
    float2 x;
    x.x = bf2f(xb.x);
    x.y = bf2f(xb.y);

    float s  = x.x + x.y;
    float sq = x.x * x.x + x.y * x.y;
#pragma unroll
    for (int off = 32; off > 0; off >>= 1) {
        s  += __shfl_xor(s, off);
        sq += __shfl_xor(sq, off);
    }
    __shared__ float rs[4], rq[4];
    const int wv = tid >> 6;
    if ((tid & 63) == 0) { rs[wv] = s; rq[wv] = sq; }
    __syncthreads();
    s  = rs[0] + rs[1] + rs[2] + rs[3];
    sq = rq[0] + rq[1] + rq[2] + rq[3];

    const float mu  = s * (1.0f / SIZE_D);
    const float var = sq * (1.0f / SIZE_D) - mu * mu;
    const float rr  = rsqrtf(var + 1e-5f);

    const float2 wv2 = *reinterpret_cast<const float2*>(&w[tid * 2]);
    const float2 bv2 = *reinterpret_cast<const float2*>(&b[tid * 2]);
    ushort2 ob;
    ob.x = f2bf((x.x - mu) * rr * wv2.x + bv2.x);
    ob.y = f2bf((x.y - mu) * rr * wv2.y + bv2.y);
    *reinterpret_cast<ushort2*>(&outb[(size_t)row * SIZE_D + tid * 2]) = ob;
}

// ---------------------------------------------------------------------------
// Fused out-proj + ReLU + residual + LN1 -> d_out. BK=32, 2 blocks/CU.
// ---------------------------------------------------------------------------
__global__ __launch_bounds__(512, 2) void oproj_ln(const unsigned short* __restrict__ X,
                                                   const unsigned short* __restrict__ W,
                                                   const float* __restrict__ bo,
                                                   const float* __restrict__ g1,
                                                   const float* __restrict__ b1,
                                                   float* __restrict__ out) {
    __shared__ __align__(16) unsigned short Ad[2][64 * 32];
    __shared__ __align__(16) unsigned short Bd[2][512 * 32];
    __shared__ float red[64][8][2];
    __shared__ float stat[64][2];

    const int tid  = threadIdx.x;
    const int wv   = tid >> 6;
    const int lane = tid & 63;
    const int bm   = blockIdx.x * 64;

    auto stage = [&](int buf, int t) {
        const int k0 = t * 32;
        if (tid < 256) {
            const int o   = tid * 16;
            const int row = o >> 6;
            const int in  = (o & 63) ^ (((row >> 1) & 3) << 4);
            gload_lds16(X + (size_t)(bm + row) * SIZE_D + k0 + (in >> 1), &Ad[buf][o >> 1]);
        }
#pragma unroll
        for (int i = 0; i < 4; ++i) {
            const int o   = i * 8192 + tid * 16;
            const int row = o >> 6;
            const int in  = (o & 63) ^ (((row >> 1) & 3) << 4);
            gload_lds16(W + (size_t)row * SIZE_D + k0 + (in >> 1), &Bd[buf][o >> 1]);
        }
    };

    f32x4 acc[4][4];
#pragma unroll
    for (int mt = 0; mt < 4; ++mt)
#pragma unroll
        for (int nt = 0; nt < 4; ++nt) acc[mt][nt] = (f32x4){0.f, 0.f, 0.f, 0.f};

    stage(0, 0);
    __syncthreads();
    int cur = 0;

    for (int t = 0; t < 16; ++t) {
        if (t < 15) stage(cur ^ 1, t + 1);

        bf16x8 af[4], bfr[4];
#pragma unroll
        for (int mt = 0; mt < 4; ++mt) {
            const int r = mt * 16 + (lane & 15);
            int byte = r * 64 + (lane >> 4) * 16;
            byte ^= ((r >> 1) & 3) << 4;
            af[mt] = *reinterpret_cast<const bf16x8*>(
                reinterpret_cast<const char*>(&Ad[cur][0]) + byte);
        }
#pragma unroll
        for (int nt = 0; nt < 4; ++nt) {
            const int r = wv * 64 + nt * 16 + (lane & 15);
            int byte = r * 64 + (lane >> 4) * 16;
            byte ^= ((r >> 1) & 3) << 4;
            bfr[nt] = *reinterpret_cast<const bf16x8*>(
                reinterpret_cast<const char*>(&Bd[cur][0]) + byte);
        }
#pragma unroll
        for (int mt = 0; mt < 4; ++mt)
#pragma unroll
            for (int nt = 0; nt < 4; ++nt)
                acc[mt][nt] = __builtin_amdgcn_mfma_f32_16x16x32_bf16(
                    af[mt], bfr[nt], acc[mt][nt], 0, 0, 0);

        __syncthreads();
        cur ^= 1;
    }

#pragma unroll
    for (int nt = 0; nt < 4; ++nt) {
        const int n  = wv * 64 + nt * 16 + (lane & 15);
        const float bc = bo[n];
#pragma unroll
        for (int mt = 0; mt < 4; ++mt) {
            const int row0 = bm + mt * 16 + (lane >> 4) * 4;
#pragma unroll
            for (int r = 0; r < 4; ++r) {
                const float R = bf2f(X[(size_t)(row0 + r) * SIZE_D + n]);
                acc[mt][nt][r] = R + fmaxf(acc[mt][nt][r] + bc, 0.0f);
            }
        }
    }

    float ps[4][4], pq[4][4];
#pragma unroll
    for (int mt = 0; mt < 4; ++mt)
#pragma unroll
        for (int r = 0; r < 4; ++r) {
            float s = 0.f, q = 0.f;
#pragma unroll
            for (int nt = 0; nt < 4; ++nt) {
                const float v = acc[mt][nt][r];
                s += v; q += v * v;
            }
#pragma unroll
            for (int off = 1; off <= 8; off <<= 1) {
                s += __shfl_xor(s, off);
                q += __shfl_xor(q, off);
            }
            ps[mt][r] = s; pq[mt][r] = q;
        }
    {
        const int mtw = (lane & 15) >> 2, rw = lane & 3;
        const int rowL = mtw * 16 + (lane >> 4) * 4 + rw;
        red[rowL][wv][0] = ps[mtw][rw];
        red[rowL][wv][1] = pq[mtw][rw];
    }
    __syncthreads();
    if (tid < 64) {
        float s = 0.f, q = 0.f;
#pragma unroll
        for (int w8 = 0; w8 < 8; ++w8) { s += red[tid][w8][0]; q += red[tid][w8][1]; }
        const float mu  = s * (1.0f / SIZE_D);
        const float var = q * (1.0f / SIZE_D) - mu * mu;
        stat[tid][0] = mu;
        stat[tid][1] = rsqrtf(var + 1e-5f);
    }
    __syncthreads();

#pragma unroll
    for (int nt = 0; nt < 4; ++nt) {
        const int n = wv * 64 + nt * 16 + (lane & 15);
        const float g = g1[n], bb = b1[n];
#pragma unroll
        for (int mt = 0; mt < 4; ++mt) {
#pragma unroll
            for (int r = 0; r < 4; ++r) {
                const int rowL = mt * 16 + (lane >> 4) * 4 + r;
                const float y = (acc[mt][nt][r] - stat[rowL][0]) * stat[rowL][1];
                out[(size_t)(bm + rowL) * SIZE_D + n] = y * g + bb;
            }
        }
    }
}

// ---------------------------------------------------------------------------
extern "C" void kernel_launch(void* const* d_in, const int* in_sizes, int n_in,
                              void* d_out, int out_size, void* d_ws, size_t ws_size,
                              hipStream_t stream) {
    const float* query = (const float*)d_in[0];
    const float* keyv  = (const float*)d_in[1];
    const float* Wq    = (const float*)d_in[2];
    const float* bq    = (const float*)d_in[3];
    const float* Wk    = (const float*)d_in[4];
    const float* bk    = (const float*)d_in[5];
    const float* Wv    = (const float*)d_in[6];
    const float* bv    = (const float*)d_in[7];
    const float* Wo    = (const float*)d_in[8];
    const float* bo    = (const float*)d_in[9];
    const float* ln0w  = (const float*)d_in[10];
    const float* ln0b  = (const float*)d_in[11];
    const float* ln1w  = (const float*)d_in[12];
    const float* ln1b  = (const float*)d_in[13];
    float* out = (float*)d_out;

    // workspace layout:
    //   [ 0,16) obf bf16 (attn output + residual)
    //   [32,48) Qh bf16 head-major -> Xbf bf16 after ln0
    //   [48,64) Kh bf16 head-major (pre-scaled)
    //   [64,80) Vt bf16 transposed [b,h,d,kv]
    //   [80,82) Wbf: [Wq;Wk;Wv;Wo] bf16 contiguous
    char* ws = (char*)d_ws;
    unsigned short* obf  = (unsigned short*)ws;
    unsigned short* Qh   = (unsigned short*)(ws + ((size_t)32 << 20));
    unsigned short* Xbf  = Qh;
    unsigned short* Kh   = (unsigned short*)(ws + ((size_t)48 << 20));
    unsigned short* Vt   = (unsigned short*)(ws + ((size_t)64 << 20));
    unsigned short* Wbf  = (unsigned short*)(ws + ((size_t)80 << 20));
    unsigned short* WoB  = Wbf + 786432;

    cvt_w4<<<dim3(64, 4), 256, 0, stream>>>(Wq, Wk, Wv, Wo, Wbf);

    gemm_proj3<<<dim3(128, 12), 256, 0, stream>>>(query, keyv, Wbf, bq, bk, bv, Qh, Kh, Vt);

    attn_mfma<<<dim3(BATCH * HEADS, 2), 256, 0, stream>>>(Qh, Kh, Vt, obf);

    ln0_bf16<<<NROWS, 256, 0, stream>>>(obf, ln0w, ln0b, Xbf);

    oproj_ln<<<NROWS / 64, 512, 0, stream>>>(Xbf, WoB, bo, ln1w, ln1b, out);
}

// Round 17
// 154.753 us; speedup vs baseline: 1.0715x; 1.0112x over previous
//
#include <hip/hip_runtime.h>

#define SIZE_D 512
#define HEADS  8
#define HDIM   64
#define BATCH  32
#define SEQ    512
#define SCALE_F 0.125f   // 1/sqrt(64)
#define NROWS  (BATCH * SEQ)   // 16384

typedef __attribute__((ext_vector_type(8))) short bf16x8;
typedef __attribute__((ext_vector_type(4))) float f32x4;
typedef __attribute__((ext_vector_type(4))) unsigned int u32x4;

__device__ __forceinline__ unsigned short f2bf(float f) {
    union { float f; unsigned int u; } c{f};
    unsigned int x = c.u;
    x += 0x7fffu + ((x >> 16) & 1u);   // RNE
    return (unsigned short)(x >> 16);
}
__device__ __forceinline__ float bf2f(unsigned short u) {
    union { unsigned int i; float f; } c;
    c.i = (unsigned int)u << 16;
    return c.f;
}
__device__ __forceinline__ unsigned int pack2bf(float lo, float hi) {
    return ((__float_as_uint(hi) + 0x8000u) & 0xffff0000u) |
           ((__float_as_uint(lo) + 0x8000u) >> 16);
}
__device__ __forceinline__ void gload_lds16(const unsigned short* g, unsigned short* l) {
    __builtin_amdgcn_global_load_lds(
        (const __attribute__((address_space(1))) unsigned int*)g,
        (__attribute__((address_space(3))) unsigned int*)l, 16, 0, 0);
}

// counted-vmcnt barrier (T4), r15-proven in gemm_proj3
#define KBAR8() do {                                                      \
    asm volatile("s_waitcnt vmcnt(8) lgkmcnt(0)" ::: "memory");           \
    __builtin_amdgcn_sched_barrier(0);                                    \
    __builtin_amdgcn_s_barrier();                                         \
    __builtin_amdgcn_sched_barrier(0);                                    \
} while (0)
#define KBAR0() do {                                                      \
    asm volatile("s_waitcnt vmcnt(0) lgkmcnt(0)" ::: "memory");           \
    __builtin_amdgcn_sched_barrier(0);                                    \
    __builtin_amdgcn_s_barrier();                                         \
    __builtin_amdgcn_sched_barrier(0);                                    \
} while (0)

// ---------------------------------------------------------------------------
// 4 weight matrices (512x512) -> contiguous bf16 [Wq;Wk;Wv;Wo]
// ---------------------------------------------------------------------------
__global__ __launch_bounds__(256) void cvt_w4(const float* __restrict__ w0,
                                              const float* __restrict__ w1,
                                              const float* __restrict__ w2,
                                              const float* __restrict__ w3,
                                              unsigned short* __restrict__ d) {
    const float* srcs[4] = {w0, w1, w2, w3};
    const float* s = srcs[blockIdx.y];
    unsigned short* dst = d + (size_t)blockIdx.y * (SIZE_D * SIZE_D);
    const int n = SIZE_D * SIZE_D;
    const int stride = gridDim.x * blockDim.x * 4;
    for (int i = (blockIdx.x * blockDim.x + threadIdx.x) * 4; i < n; i += stride) {
        const float4 v = *reinterpret_cast<const float4*>(s + i);
        ushort4 o;
        o.x = f2bf(v.x); o.y = f2bf(v.y); o.z = f2bf(v.z); o.w = f2bf(v.w);
        *reinterpret_cast<ushort4*>(dst + i) = o;
    }
}

// ---------------------------------------------------------------------------
// Merged projection GEMM (r15-proven): f32 A, BK=64, 2-deep A pipeline,
// counted-vmcnt barriers. grid (128,12): y 0..3 Q->Qh; 4..7 K->Kh
// (prescaled); 8..11 V->Vt.
// ---------------------------------------------------------------------------
__global__ __launch_bounds__(256, 2) void gemm_proj3(const float* __restrict__ query,
                                                     const float* __restrict__ keyv,
                                                     const unsigned short* __restrict__ Wall,
                                                     const float* __restrict__ bq,
                                                     const float* __restrict__ bk,
                                                     const float* __restrict__ bv,
                                                     unsigned short* __restrict__ Qh,
                                                     unsigned short* __restrict__ Kh,
                                                     unsigned short* __restrict__ Vt) {
    __shared__ __align__(16) unsigned short Ad[2][128 * 64];
    __shared__ __align__(16) unsigned short Bd[2][128 * 64];

    const int tid  = threadIdx.x;
    const int wv   = tid >> 6;
    const int lane = tid & 63;
    const int y    = blockIdx.y;
    const int bm   = blockIdx.x * 128;
    const int bn   = y * 128;
    const int wr   = wv >> 1;
    const int wc   = wv & 1;

    const float* A = (y < 4) ? query : keyv;

    float4 areg[2][4][2];

    auto loadA = [&](int t, int slot) {
        const int k0 = t * 64;
#pragma unroll
        for (int i = 0; i < 4; ++i) {
            const int o   = (wv * 32 + i * 8) * 128 + lane * 16;
            const int row = o >> 7;
            const int col = ((o & 127) ^ ((row & 7) << 4)) >> 1;
            const float* src = A + (size_t)(bm + row) * SIZE_D + k0 + col;
            areg[slot][i][0] = *reinterpret_cast<const float4*>(src);
            areg[slot][i][1] = *reinterpret_cast<const float4*>(src + 4);
        }
    };
    auto writeA = [&](int buf, int slot) {
#pragma unroll
        for (int i = 0; i < 4; ++i) {
            const int o = (wv * 32 + i * 8) * 128 + lane * 16;
            union { unsigned int u[4]; bf16x8 v; } pk;
            pk.u[0] = pack2bf(areg[slot][i][0].x, areg[slot][i][0].y);
            pk.u[1] = pack2bf(areg[slot][i][0].z, areg[slot][i][0].w);
            pk.u[2] = pack2bf(areg[slot][i][1].x, areg[slot][i][1].y);
            pk.u[3] = pack2bf(areg[slot][i][1].z, areg[slot][i][1].w);
            *reinterpret_cast<bf16x8*>(&Ad[buf][o >> 1]) = pk.v;
        }
    };
    auto stageW = [&](int buf, int t) {
        const int k0 = t * 64;
#pragma unroll
        for (int i = 0; i < 4; ++i) {
            const int o   = (wv * 32 + i * 8) * 128 + lane * 16;
            const int row = o >> 7;
            const int col = ((o & 127) ^ ((row & 7) << 4)) >> 1;
            gload_lds16(Wall + (size_t)(bn + row) * SIZE_D + k0 + col, &Bd[buf][o >> 1]);
        }
    };

    f32x4 acc[4][4];
#pragma unroll
    for (int mt = 0; mt < 4; ++mt)
#pragma unroll
        for (int nt = 0; nt < 4; ++nt) acc[mt][nt] = (f32x4){0.f, 0.f, 0.f, 0.f};

    loadA(0, 0);
    stageW(0, 0);
    writeA(0, 0);
    loadA(1, 1);

#pragma unroll
    for (int t = 0; t < 8; ++t) {
        const int cur = t & 1;
        if (t < 7) { KBAR8(); } else { KBAR0(); }

        if (t < 7) stageW(cur ^ 1, t + 1);
        if (t < 6) loadA(t + 2, t & 1);

        bf16x8 af[2][4], bfr[2][4];
#pragma unroll
        for (int kc = 0; kc < 2; ++kc) {
#pragma unroll
            for (int mt = 0; mt < 4; ++mt) {
                const int r = wr * 64 + mt * 16 + (lane & 15);
                int byte = r * 128 + kc * 64 + (lane >> 4) * 16;
                byte ^= (r & 7) << 4;
                af[kc][mt] = *reinterpret_cast<const bf16x8*>(
                    reinterpret_cast<const char*>(&Ad[cur][0]) + byte);
            }
#pragma unroll
            for (int nt = 0; nt < 4; ++nt) {
                const int r = wc * 64 + nt * 16 + (lane & 15);
                int byte = r * 128 + kc * 64 + (lane >> 4) * 16;
                byte ^= (r & 7) << 4;
                bfr[kc][nt] = *reinterpret_cast<const bf16x8*>(
                    reinterpret_cast<const char*>(&Bd[cur][0]) + byte);
            }
        }
#pragma unroll
        for (int kc = 0; kc < 2; ++kc)
#pragma unroll
            for (int mt = 0; mt < 4; ++mt)
#pragma unroll
                for (int nt = 0; nt < 4; ++nt)
                    acc[mt][nt] = __builtin_amdgcn_mfma_f32_16x16x32_bf16(
                        af[kc][mt], bfr[kc][nt], acc[mt][nt], 0, 0, 0);

        if (t < 7) writeA(cur ^ 1, (t + 1) & 1);
    }

    if (y < 8) {
        const float* bias = (y < 4) ? bq : bk;
        unsigned short* D = (y < 4) ? Qh : Kh;
        const int coff = (y < 4) ? 0 : 512;
#pragma unroll
        for (int nt = 0; nt < 4; ++nt) {
            const int colL = bn - coff + wc * 64 + nt * 16 + (lane & 15);
            const float bc = bias[colL];
            const int h = colL >> 6, dd = colL & 63;
#pragma unroll
            for (int mt = 0; mt < 4; ++mt) {
                const int row0 = bm + wr * 64 + mt * 16 + (lane >> 4) * 4;
#pragma unroll
                for (int r = 0; r < 4; ++r) {
                    const int row = row0 + r;
                    const int b_ = row >> 9, l = row & 511;
                    float z = acc[mt][nt][r] + bc;
                    if (y >= 4) z *= SCALE_F;
                    D[(((size_t)b_ * HEADS + h) * SEQ + l) * HDIM + dd] = f2bf(z);
                }
            }
        }
    } else {
#pragma unroll
        for (int nt = 0; nt < 4; ++nt) {
            const int c2 = bn - 1024 + wc * 64 + nt * 16 + (lane & 15);
            const float bc = bv[c2];
            const int hV = c2 >> 6, dV = c2 & 63;
#pragma unroll
            for (int mt = 0; mt < 4; ++mt) {
                const int row0 = bm + wr * 64 + mt * 16 + (lane >> 4) * 4;
                const int b_ = row0 >> 9, kv = row0 & 511;
                ushort4 pk;
                pk.x = f2bf(acc[mt][nt][0] + bc);
                pk.y = f2bf(acc[mt][nt][1] + bc);
                pk.z = f2bf(acc[mt][nt][2] + bc);
                pk.w = f2bf(acc[mt][nt][3] + bc);
                *reinterpret_cast<ushort4*>(
                    &Vt[(((size_t)b_ * HEADS + hV) * HDIM + dV) * SEQ + kv]) = pk;
            }
        }
    }
}

// ---------------------------------------------------------------------------
// MFMA attention — r16 shell (bf16 out + setprio); poly trimmed to 2 fma.
// ---------------------------------------------------------------------------
__global__ __launch_bounds__(256, 2) void attn_mfma(const unsigned short* __restrict__ Qh,
                                                    const unsigned short* __restrict__ Kh,
                                                    const unsigned short* __restrict__ Vt,
                                                    unsigned short* __restrict__ outb) {
    __shared__ __align__(16) unsigned short Kt[2][64 * 64];   // [kv][d] swizzled
    __shared__ __align__(16) unsigned short Vs[2][64 * 64];   // [d][kv] swizzled

    const int tid  = threadIdx.x;
    const int wv   = tid >> 6;
    const int lane = tid & 63;
    const int bh   = blockIdx.x;
    const int b    = bh >> 3;
    const int h    = bh & 7;
    const int g    = lane >> 4;

    const unsigned short* Qb = Qh + (size_t)bh * (SEQ * HDIM);
    const unsigned short* Kb = Kh + (size_t)bh * (SEQ * HDIM);
    const unsigned short* Vb = Vt + (size_t)bh * (HDIM * SEQ);

    const int m0 = blockIdx.y * 256 + wv * 64;

    auto stageKV = [&](int buf, int t) {
        const int kv0 = t * 64;
#pragma unroll
        for (int i = 0; i < 2; ++i) {
            const int o   = i * 4096 + tid * 16;
            const int row = o >> 7;
            const int in  = (o & 127) ^ ((row & 7) << 4);
            gload_lds16(Kb + (size_t)(kv0 + row) * HDIM + (in >> 1), &Kt[buf][o >> 1]);
            gload_lds16(Vb + (size_t)row * SEQ + kv0 + (in >> 1), &Vs[buf][o >> 1]);
        }
    };

    bf16x8 qf[4][2];
#pragma unroll
    for (int mt = 0; mt < 4; ++mt)
#pragma unroll
        for (int kc = 0; kc < 2; ++kc) {
            const int m = m0 + mt * 16 + (lane & 15);
            union { u32x4 u; bf16x8 v; } cv;
            cv.u = *reinterpret_cast<const u32x4*>(
                Qb + (size_t)m * HDIM + kc * 32 + g * 8);
            qf[mt][kc] = cv.v;
        }

    f32x4 oacc[4][4];
    float esum[4] = {0.f, 0.f, 0.f, 0.f};
#pragma unroll
    for (int mt = 0; mt < 4; ++mt)
#pragma unroll
        for (int x = 0; x < 4; ++x) oacc[mt][x] = (f32x4){0.f, 0.f, 0.f, 0.f};

    stageKV(0, 0);
    __syncthreads();
    int cur = 0;

    for (int t = 0; t < 8; ++t) {
        if (t < 7) stageKV(cur ^ 1, t + 1);

        f32x4 sacc[4][4];
#pragma unroll
        for (int nt = 0; nt < 4; ++nt)
#pragma unroll
            for (int mt = 0; mt < 4; ++mt) sacc[nt][mt] = (f32x4){0.f, 0.f, 0.f, 0.f};

#pragma unroll
        for (int kc = 0; kc < 2; ++kc) {
            bf16x8 kf[4];
#pragma unroll
            for (int nt = 0; nt < 4; ++nt) {
                const int kvl = nt * 16 + (lane & 15);
                int byte = kvl * 128 + kc * 64 + g * 16;
                byte ^= (kvl & 7) << 4;
                kf[nt] = *reinterpret_cast<const bf16x8*>(
                    reinterpret_cast<const char*>(&Kt[cur][0]) + byte);
            }
            __builtin_amdgcn_s_setprio(1);
#pragma unroll
            for (int nt = 0; nt < 4; ++nt)
#pragma unroll
                for (int mt = 0; mt < 4; ++mt)
                    sacc[nt][mt] = __builtin_amdgcn_mfma_f32_16x16x32_bf16(
                        kf[nt], qf[mt][kc], sacc[nt][mt], 0, 0, 0);
            __builtin_amdgcn_s_setprio(0);
        }

        bf16x8 pa[2][4];
#pragma unroll
        for (int c = 0; c < 2; ++c)
#pragma unroll
            for (int mt = 0; mt < 4; ++mt) {
                float w[8];
#pragma unroll
                for (int j = 0; j < 8; ++j) {
                    const float s  = sacc[2 * c + (j >> 2)][mt][j & 3];
                    const float a  = fminf(fabsf(s), 30.0f);
                    const float tt = __expf(a);
                    const float t2 = tt * tt;
                    const float u  = __builtin_amdgcn_sqrtf(fmaf(s, s, 0.01f));
                    const float dl = u - a;                     // <= 0.1
                    const float ed = fmaf(dl, fmaf(dl, 0.5f, 1.0f), 1.0f);
                    const float eu = tt * ed;
                    esum[mt] += eu;
                    const float th = fmaf(-2.0f, __builtin_amdgcn_rcpf(t2 + 1.0f), 1.0f);
                    w[j] = __builtin_copysignf(th * eu, s);
                }
                union { unsigned int u[4]; bf16x8 v; } pk;
#pragma unroll
                for (int p = 0; p < 4; ++p)
                    pk.u[p] = (__float_as_uint(w[2 * p + 1]) & 0xffff0000u) |
                              (__float_as_uint(w[2 * p]) >> 16);
                pa[c][mt] = pk.v;
            }

#pragma unroll
        for (int c = 0; c < 2; ++c) {
            bf16x8 vf[4];
#pragma unroll
            for (int dt = 0; dt < 4; ++dt) {
                const int d = dt * 16 + (lane & 15);
                const int swz = (d & 7) << 4;
                const int rowb = d * 128;
                uint2 lo = *reinterpret_cast<const uint2*>(
                    reinterpret_cast<const char*>(&Vs[cur][0]) +
                    (rowb + (((c * 32 + 4 * g) * 2) ^ swz)));
                uint2 hi = *reinterpret_cast<const uint2*>(
                    reinterpret_cast<const char*>(&Vs[cur][0]) +
                    (rowb + (((c * 32 + 16 + 4 * g) * 2) ^ swz)));
                union { unsigned int u[4]; bf16x8 v; } cvb;
                cvb.u[0] = lo.x; cvb.u[1] = lo.y;
                cvb.u[2] = hi.x; cvb.u[3] = hi.y;
                vf[dt] = cvb.v;
            }
            __builtin_amdgcn_s_setprio(1);
#pragma unroll
            for (int mt = 0; mt < 4; ++mt)
#pragma unroll
                for (int dt = 0; dt < 4; ++dt)
                    oacc[mt][dt] = __builtin_amdgcn_mfma_f32_16x16x32_bf16(
                        pa[c][mt], vf[dt], oacc[mt][dt], 0, 0, 0);
            __builtin_amdgcn_s_setprio(0);
        }

        __syncthreads();
        cur ^= 1;
    }

    float rden[4];
#pragma unroll
    for (int mt = 0; mt < 4; ++mt) {
        float e = esum[mt];
        e += __shfl_xor(e, 16);
        e += __shfl_xor(e, 32);
        rden[mt] = __builtin_amdgcn_rcpf(e);
    }
    float rr_[4][4];
#pragma unroll
    for (int mt = 0; mt < 4; ++mt)
#pragma unroll
        for (int r = 0; r < 4; ++r)
            rr_[mt][r] = __shfl(rden[mt], g * 4 + r);

#pragma unroll
    for (int mt = 0; mt < 4; ++mt)
#pragma unroll
        for (int dt = 0; dt < 4; ++dt)
#pragma unroll
            for (int r = 0; r < 4; ++r) {
                const int m = m0 + mt * 16 + g * 4 + r;
                const int d = dt * 16 + (lane & 15);
                const float qv = bf2f(Qb[(size_t)m * HDIM + d]);
                outb[((size_t)b * SEQ + m) * SIZE_D + h * HDIM + d] =
                    f2bf(qv + oacc[mt][dt][r] * rr_[mt][r]);
            }
}

// ---------------------------------------------------------------------------
// LN0: bf16 in -> bf16 out (serves as GEMM-A and residual R)
// ---------------------------------------------------------------------------
__global__ __launch_bounds__(256) void ln0_bf16(const unsigned short* __restrict__ in,
                                                const float* __restrict__ w,
                                                const float* __restrict__ b,
                                                unsigned short* __restrict__ outb) {
    const int row = blockIdx.x;
    const int tid = threadIdx.x;
    const ushort2 xb = *reinterpret_cast<const ushort2*>(&in[(size_t)row * SIZE_D + tid * 2]);
    float2 x;
    x.x = bf2f(xb.x);
    x.y = bf2f(xb.y);

    float s  = x.x + x.y;
    float sq = x.x * x.x + x.y * x.y;
#pragma unroll
    for (int off = 32; off > 0; off >>= 1) {
        s  += __shfl_xor(s, off);
        sq += __shfl_xor(sq, off);
    }
    __shared__ float rs[4], rq[4];
    const int wv = tid >> 6;
    if ((tid & 63) == 0) { rs[wv] = s; rq[wv] = sq; }
    __syncthreads();
    s  = rs[0] + rs[1] + rs[2] + rs[3];
    sq = rq[0] + rq[1] + rq[2] + rq[3];

    const float mu  = s * (1.0f / SIZE_D);
    const float var = sq * (1.0f / SIZE_D) - mu * mu;
    const float rr  = rsqrtf(var + 1e-5f);

    const float2 wv2 = *reinterpret_cast<const float2*>(&w[tid * 2]);
    const float2 bv2 = *reinterpret_cast<const float2*>(&b[tid * 2]);
    ushort2 ob;
    ob.x = f2bf((x.x - mu) * rr * wv2.x + bv2.x);
    ob.y = f2bf((x.y - mu) * rr * wv2.y + bv2.y);
    *reinterpret_cast<ushort2*>(&outb[(size_t)row * SIZE_D + tid * 2]) = ob;
}

// ---------------------------------------------------------------------------
// Fused out-proj + ReLU + residual + LN1 -> d_out.
// BM=32 (grid 512 -> 2 blocks/CU, 4 waves/SIMD), BK=32.
// Wave wv owns cols [wv*64, wv*64+64); per-wave frags acc[2][4].
// ---------------------------------------------------------------------------
__global__ __launch_bounds__(512, 2) void oproj_ln(const unsigned short* __restrict__ X,
                                                   const unsigned short* __restrict__ W,
                                                   const float* __restrict__ bo,
                                                   const float* __restrict__ g1,
                                                   const float* __restrict__ b1,
                                                   float* __restrict__ out) {
    __shared__ __align__(16) unsigned short Ad[2][32 * 32];    // 2KB x2
    __shared__ __align__(16) unsigned short Bd[2][512 * 32];   // 32KB x2
    __shared__ float red[32][8][2];                            // 2KB
    __shared__ float stat[32][2];

    const int tid  = threadIdx.x;
    const int wv   = tid >> 6;
    const int lane = tid & 63;
    const int bm   = blockIdx.x * 32;

    auto stage = [&](int buf, int t) {
        const int k0 = t * 32;
        if (tid < 128) {
            const int o   = tid * 16;
            const int row = o >> 6;
            const int in  = (o & 63) ^ (((row >> 1) & 3) << 4);
            gload_lds16(X + (size_t)(bm + row) * SIZE_D + k0 + (in >> 1), &Ad[buf][o >> 1]);
        }
#pragma unroll
        for (int i = 0; i < 4; ++i) {
            const int o   = i * 8192 + tid * 16;
            const int row = o >> 6;
            const int in  = (o & 63) ^ (((row >> 1) & 3) << 4);
            gload_lds16(W + (size_t)row * SIZE_D + k0 + (in >> 1), &Bd[buf][o >> 1]);
        }
    };

    f32x4 acc[2][4];
#pragma unroll
    for (int mt = 0; mt < 2; ++mt)
#pragma unroll
        for (int nt = 0; nt < 4; ++nt) acc[mt][nt] = (f32x4){0.f, 0.f, 0.f, 0.f};

    stage(0, 0);
    __syncthreads();
    int cur = 0;

    for (int t = 0; t < 16; ++t) {
        if (t < 15) stage(cur ^ 1, t + 1);

        bf16x8 af[2], bfr[4];
#pragma unroll
        for (int mt = 0; mt < 2; ++mt) {
            const int r = mt * 16 + (lane & 15);
            int byte = r * 64 + (lane >> 4) * 16;
            byte ^= ((r >> 1) & 3) << 4;
            af[mt] = *reinterpret_cast<const bf16x8*>(
                reinterpret_cast<const char*>(&Ad[cur][0]) + byte);
        }
#pragma unroll
        for (int nt = 0; nt < 4; ++nt) {
            const int r = wv * 64 + nt * 16 + (lane & 15);
            int byte = r * 64 + (lane >> 4) * 16;
            byte ^= ((r >> 1) & 3) << 4;
            bfr[nt] = *reinterpret_cast<const bf16x8*>(
                reinterpret_cast<const char*>(&Bd[cur][0]) + byte);
        }
#pragma unroll
        for (int mt = 0; mt < 2; ++mt)
#pragma unroll
            for (int nt = 0; nt < 4; ++nt)
                acc[mt][nt] = __builtin_amdgcn_mfma_f32_16x16x32_bf16(
                    af[mt], bfr[nt], acc[mt][nt], 0, 0, 0);

        __syncthreads();
        cur ^= 1;
    }

    // epilogue pass 1: y = R + relu(z + bo)
#pragma unroll
    for (int nt = 0; nt < 4; ++nt) {
        const int n  = wv * 64 + nt * 16 + (lane & 15);
        const float bc = bo[n];
#pragma unroll
        for (int mt = 0; mt < 2; ++mt) {
            const int row0 = bm + mt * 16 + (lane >> 4) * 4;
#pragma unroll
            for (int r = 0; r < 4; ++r) {
                const float R = bf2f(X[(size_t)(row0 + r) * SIZE_D + n]);
                acc[mt][nt][r] = R + fmaxf(acc[mt][nt][r] + bc, 0.0f);
            }
        }
    }

    // LN1 row stats: per-lane partials, 16-lane butterfly, 1 writer/row
    float ps[2][4], pq[2][4];
#pragma unroll
    for (int mt = 0; mt < 2; ++mt)
#pragma unroll
        for (int r = 0; r < 4; ++r) {
            float s = 0.f, q = 0.f;
#pragma unroll
            for (int nt = 0; nt < 4; ++nt) {
                const float v = acc[mt][nt][r];
                s += v; q += v * v;
            }
#pragma unroll
            for (int off = 1; off <= 8; off <<= 1) {
                s += __shfl_xor(s, off);
                q += __shfl_xor(q, off);
            }
            ps[mt][r] = s; pq[mt][r] = q;
        }
    if ((lane & 15) < 8) {
        const int mtw = (lane & 15) >> 2;   // 0..1
        const int rw  = lane & 3;
        const int rowL = mtw * 16 + (lane >> 4) * 4 + rw;
        red[rowL][wv][0] = ps[mtw][rw];
        red[rowL][wv][1] = pq[mtw][rw];
    }
    __syncthreads();
    if (tid < 32) {
        float s = 0.f, q = 0.f;
#pragma unroll
        for (int w8 = 0; w8 < 8; ++w8) { s += red[tid][w8][0]; q += red[tid][w8][1]; }
        const float mu  = s * (1.0f / SIZE_D);
        const float var = q * (1.0f / SIZE_D) - mu * mu;
        stat[tid][0] = mu;
        stat[tid][1] = rsqrtf(var + 1e-5f);
    }
    __syncthreads();

    // normalize + write
#pragma unroll
    for (int nt = 0; nt < 4; ++nt) {
        const int n = wv * 64 + nt * 16 + (lane & 15);
        const float g = g1[n], bb = b1[n];
#pragma unroll
        for (int mt = 0; mt < 2; ++mt) {
#pragma unroll
            for (int r = 0; r < 4; ++r) {
                const int rowL = mt * 16 + (lane >> 4) * 4 + r;
                const float y = (acc[mt][nt][r] - stat[rowL][0]) * stat[rowL][1];
                out[(size_t)(bm + rowL) * SIZE_D + n] = y * g + bb;
            }
        }
    }
}

// ---------------------------------------------------------------------------
extern "C" void kernel_launch(void* const* d_in, const int* in_sizes, int n_in,
                              void* d_out, int out_size, void* d_ws, size_t ws_size,
                              hipStream_t stream) {
    const float* query = (const float*)d_in[0];
    const float* keyv  = (const float*)d_in[1];
    const float* Wq    = (const float*)d_in[2];
    const float* bq    = (const float*)d_in[3];
    const float* Wk    = (const float*)d_in[4];
    const float* bk    = (const float*)d_in[5];
    const float* Wv    = (const float*)d_in[6];
    const float* bv    = (const float*)d_in[7];
    const float* Wo    = (const float*)d_in[8];
    const float* bo    = (const float*)d_in[9];
    const float* ln0w  = (const float*)d_in[10];
    const float* ln0b  = (const float*)d_in[11];
    const float* ln1w  = (const float*)d_in[12];
    const float* ln1b  = (const float*)d_in[13];
    float* out = (float*)d_out;

    // workspace layout:
    //   [ 0,16) obf bf16 (attn output + residual)
    //   [32,48) Qh bf16 head-major -> Xbf bf16 after ln0
    //   [48,64) Kh bf16 head-major (pre-scaled)
    //   [64,80) Vt bf16 transposed [b,h,d,kv]
    //   [80,82) Wbf: [Wq;Wk;Wv;Wo] bf16 contiguous
    char* ws = (char*)d_ws;
    unsigned short* obf  = (unsigned short*)ws;
    unsigned short* Qh   = (unsigned short*)(ws + ((size_t)32 << 20));
    unsigned short* Xbf  = Qh;
    unsigned short* Kh   = (unsigned short*)(ws + ((size_t)48 << 20));
    unsigned short* Vt   = (unsigned short*)(ws + ((size_t)64 << 20));
    unsigned short* Wbf  = (unsigned short*)(ws + ((size_t)80 << 20));
    unsigned short* WoB  = Wbf + 786432;

    cvt_w4<<<dim3(64, 4), 256, 0, stream>>>(Wq, Wk, Wv, Wo, Wbf);

    gemm_proj3<<<dim3(128, 12), 256, 0, stream>>>(query, keyv, Wbf, bq, bk, bv, Qh, Kh, Vt);

    attn_mfma<<<dim3(BATCH * HEADS, 2), 256, 0, stream>>>(Qh, Kh, Vt, obf);

    ln0_bf16<<<NROWS, 256, 0, stream>>>(obf, ln0w, ln0b, Xbf);

    oproj_ln<<<NROWS / 32, 512, 0, stream>>>(Xbf, WoB, bo, ln1w, ln1b, out);
}

// Round 18
// 146.787 us; speedup vs baseline: 1.1297x; 1.0543x over previous
//
#include <hip/hip_runtime.h>

#define SIZE_D 512
#define HEADS  8
#define HDIM   64
#define BATCH  32
#define SEQ    512
#define SCALE_F 0.125f   // 1/sqrt(64)
#define NROWS  (BATCH * SEQ)   // 16384

typedef __attribute__((ext_vector_type(8))) short bf16x8;
typedef __attribute__((ext_vector_type(4))) float f32x4;
typedef __attribute__((ext_vector_type(4))) unsigned int u32x4;

__device__ __forceinline__ unsigned short f2bf(float f) {
    union { float f; unsigned int u; } c{f};
    unsigned int x = c.u;
    x += 0x7fffu + ((x >> 16) & 1u);   // RNE
    return (unsigned short)(x >> 16);
}
__device__ __forceinline__ float bf2f(unsigned short u) {
    union { unsigned int i; float f; } c;
    c.i = (unsigned int)u << 16;
    return c.f;
}
__device__ __forceinline__ unsigned int pack2bf(float lo, float hi) {
    return ((__float_as_uint(hi) + 0x8000u) & 0xffff0000u) |
           ((__float_as_uint(lo) + 0x8000u) >> 16);
}
__device__ __forceinline__ void gload_lds16(const unsigned short* g, unsigned short* l) {
    __builtin_amdgcn_global_load_lds(
        (const __attribute__((address_space(1))) unsigned int*)g,
        (__attribute__((address_space(3))) unsigned int*)l, 16, 0, 0);
}

// counted-vmcnt barrier (T4), r15-proven in gemm_proj3
#define KBAR8() do {                                                      \
    asm volatile("s_waitcnt vmcnt(8) lgkmcnt(0)" ::: "memory");           \
    __builtin_amdgcn_sched_barrier(0);                                    \
    __builtin_amdgcn_s_barrier();                                         \
    __builtin_amdgcn_sched_barrier(0);                                    \
} while (0)
#define KBAR0() do {                                                      \
    asm volatile("s_waitcnt vmcnt(0) lgkmcnt(0)" ::: "memory");           \
    __builtin_amdgcn_sched_barrier(0);                                    \
    __builtin_amdgcn_s_barrier();                                         \
    __builtin_amdgcn_sched_barrier(0);                                    \
} while (0)

// ---------------------------------------------------------------------------
// 4 weight matrices (512x512) -> contiguous bf16 [Wq;Wk;Wv;Wo]
// ---------------------------------------------------------------------------
__global__ __launch_bounds__(256) void cvt_w4(const float* __restrict__ w0,
                                              const float* __restrict__ w1,
                                              const float* __restrict__ w2,
                                              const float* __restrict__ w3,
                                              unsigned short* __restrict__ d) {
    const float* srcs[4] = {w0, w1, w2, w3};
    const float* s = srcs[blockIdx.y];
    unsigned short* dst = d + (size_t)blockIdx.y * (SIZE_D * SIZE_D);
    const int n = SIZE_D * SIZE_D;
    const int stride = gridDim.x * blockDim.x * 4;
    for (int i = (blockIdx.x * blockDim.x + threadIdx.x) * 4; i < n; i += stride) {
        const float4 v = *reinterpret_cast<const float4*>(s + i);
        ushort4 o;
        o.x = f2bf(v.x); o.y = f2bf(v.y); o.z = f2bf(v.z); o.w = f2bf(v.w);
        *reinterpret_cast<ushort4*>(dst + i) = o;
    }
}

// ---------------------------------------------------------------------------
// Merged projection GEMM (r15-proven): f32 A, BK=64, 2-deep A pipeline,
// counted-vmcnt barriers. grid (128,12): y 0..3 Q->Qh; 4..7 K->Kh
// (prescaled); 8..11 V->Vt.
// ---------------------------------------------------------------------------
__global__ __launch_bounds__(256, 2) void gemm_proj3(const float* __restrict__ query,
                                                     const float* __restrict__ keyv,
                                                     const unsigned short* __restrict__ Wall,
                                                     const float* __restrict__ bq,
                                                     const float* __restrict__ bk,
                                                     const float* __restrict__ bv,
                                                     unsigned short* __restrict__ Qh,
                                                     unsigned short* __restrict__ Kh,
                                                     unsigned short* __restrict__ Vt) {
    __shared__ __align__(16) unsigned short Ad[2][128 * 64];
    __shared__ __align__(16) unsigned short Bd[2][128 * 64];

    const int tid  = threadIdx.x;
    const int wv   = tid >> 6;
    const int lane = tid & 63;
    const int y    = blockIdx.y;
    const int bm   = blockIdx.x * 128;
    const int bn   = y * 128;
    const int wr   = wv >> 1;
    const int wc   = wv & 1;

    const float* A = (y < 4) ? query : keyv;

    float4 areg[2][4][2];

    auto loadA = [&](int t, int slot) {
        const int k0 = t * 64;
#pragma unroll
        for (int i = 0; i < 4; ++i) {
            const int o   = (wv * 32 + i * 8) * 128 + lane * 16;
            const int row = o >> 7;
            const int col = ((o & 127) ^ ((row & 7) << 4)) >> 1;
            const float* src = A + (size_t)(bm + row) * SIZE_D + k0 + col;
            areg[slot][i][0] = *reinterpret_cast<const float4*>(src);
            areg[slot][i][1] = *reinterpret_cast<const float4*>(src + 4);
        }
    };
    auto writeA = [&](int buf, int slot) {
#pragma unroll
        for (int i = 0; i < 4; ++i) {
            const int o = (wv * 32 + i * 8) * 128 + lane * 16;
            union { unsigned int u[4]; bf16x8 v; } pk;
            pk.u[0] = pack2bf(areg[slot][i][0].x, areg[slot][i][0].y);
            pk.u[1] = pack2bf(areg[slot][i][0].z, areg[slot][i][0].w);
            pk.u[2] = pack2bf(areg[slot][i][1].x, areg[slot][i][1].y);
            pk.u[3] = pack2bf(areg[slot][i][1].z, areg[slot][i][1].w);
            *reinterpret_cast<bf16x8*>(&Ad[buf][o >> 1]) = pk.v;
        }
    };
    auto stageW = [&](int buf, int t) {
        const int k0 = t * 64;
#pragma unroll
        for (int i = 0; i < 4; ++i) {
            const int o   = (wv * 32 + i * 8) * 128 + lane * 16;
            const int row = o >> 7;
            const int col = ((o & 127) ^ ((row & 7) << 4)) >> 1;
            gload_lds16(Wall + (size_t)(bn + row) * SIZE_D + k0 + col, &Bd[buf][o >> 1]);
        }
    };

    f32x4 acc[4][4];
#pragma unroll
    for (int mt = 0; mt < 4; ++mt)
#pragma unroll
        for (int nt = 0; nt < 4; ++nt) acc[mt][nt] = (f32x4){0.f, 0.f, 0.f, 0.f};

    loadA(0, 0);
    stageW(0, 0);
    writeA(0, 0);
    loadA(1, 1);

#pragma unroll
    for (int t = 0; t < 8; ++t) {
        const int cur = t & 1;
        if (t < 7) { KBAR8(); } else { KBAR0(); }

        if (t < 7) stageW(cur ^ 1, t + 1);
        if (t < 6) loadA(t + 2, t & 1);

        bf16x8 af[2][4], bfr[2][4];
#pragma unroll
        for (int kc = 0; kc < 2; ++kc) {
#pragma unroll
            for (int mt = 0; mt < 4; ++mt) {
                const int r = wr * 64 + mt * 16 + (lane & 15);
                int byte = r * 128 + kc * 64 + (lane >> 4) * 16;
                byte ^= (r & 7) << 4;
                af[kc][mt] = *reinterpret_cast<const bf16x8*>(
                    reinterpret_cast<const char*>(&Ad[cur][0]) + byte);
            }
#pragma unroll
            for (int nt = 0; nt < 4; ++nt) {
                const int r = wc * 64 + nt * 16 + (lane & 15);
                int byte = r * 128 + kc * 64 + (lane >> 4) * 16;
                byte ^= (r & 7) << 4;
                bfr[kc][nt] = *reinterpret_cast<const bf16x8*>(
                    reinterpret_cast<const char*>(&Bd[cur][0]) + byte);
            }
        }
#pragma unroll
        for (int kc = 0; kc < 2; ++kc)
#pragma unroll
            for (int mt = 0; mt < 4; ++mt)
#pragma unroll
                for (int nt = 0; nt < 4; ++nt)
                    acc[mt][nt] = __builtin_amdgcn_mfma_f32_16x16x32_bf16(
                        af[kc][mt], bfr[kc][nt], acc[mt][nt], 0, 0, 0);

        if (t < 7) writeA(cur ^ 1, (t + 1) & 1);
    }

    if (y < 8) {
        const float* bias = (y < 4) ? bq : bk;
        unsigned short* D = (y < 4) ? Qh : Kh;
        const int coff = (y < 4) ? 0 : 512;
#pragma unroll
        for (int nt = 0; nt < 4; ++nt) {
            const int colL = bn - coff + wc * 64 + nt * 16 + (lane & 15);
            const float bc = bias[colL];
            const int h = colL >> 6, dd = colL & 63;
#pragma unroll
            for (int mt = 0; mt < 4; ++mt) {
                const int row0 = bm + wr * 64 + mt * 16 + (lane >> 4) * 4;
#pragma unroll
                for (int r = 0; r < 4; ++r) {
                    const int row = row0 + r;
                    const int b_ = row >> 9, l = row & 511;
                    float z = acc[mt][nt][r] + bc;
                    if (y >= 4) z *= SCALE_F;
                    D[(((size_t)b_ * HEADS + h) * SEQ + l) * HDIM + dd] = f2bf(z);
                }
            }
        }
    } else {
#pragma unroll
        for (int nt = 0; nt < 4; ++nt) {
            const int c2 = bn - 1024 + wc * 64 + nt * 16 + (lane & 15);
            const float bc = bv[c2];
            const int hV = c2 >> 6, dV = c2 & 63;
#pragma unroll
            for (int mt = 0; mt < 4; ++mt) {
                const int row0 = bm + wr * 64 + mt * 16 + (lane >> 4) * 4;
                const int b_ = row0 >> 9, kv = row0 & 511;
                ushort4 pk;
                pk.x = f2bf(acc[mt][nt][0] + bc);
                pk.y = f2bf(acc[mt][nt][1] + bc);
                pk.z = f2bf(acc[mt][nt][2] + bc);
                pk.w = f2bf(acc[mt][nt][3] + bc);
                *reinterpret_cast<ushort4*>(
                    &Vt[(((size_t)b_ * HEADS + hV) * HDIM + dV) * SEQ + kv]) = pk;
            }
        }
    }
}

// ---------------------------------------------------------------------------
// MFMA attention — r16 shell with 4-buffer staging: one __syncthreads per
// 2 tiles (stages t+2,t+3 while computing t,t+1; disjoint buffers).
// bf16 out + residual, setprio around MFMA clusters, 2-fma exp poly,
// no clamp (|s| << 30 by construction).
// ---------------------------------------------------------------------------
__global__ __launch_bounds__(256, 2) void attn_mfma(const unsigned short* __restrict__ Qh,
                                                    const unsigned short* __restrict__ Kh,
                                                    const unsigned short* __restrict__ Vt,
                                                    unsigned short* __restrict__ outb) {
    __shared__ __align__(16) unsigned short Kt[4][64 * 64];   // [kv][d] swizzled, 32KB
    __shared__ __align__(16) unsigned short Vs[4][64 * 64];   // [d][kv] swizzled, 32KB

    const int tid  = threadIdx.x;
    const int wv   = tid >> 6;
    const int lane = tid & 63;
    const int bh   = blockIdx.x;
    const int b    = bh >> 3;
    const int h    = bh & 7;
    const int g    = lane >> 4;

    const unsigned short* Qb = Qh + (size_t)bh * (SEQ * HDIM);
    const unsigned short* Kb = Kh + (size_t)bh * (SEQ * HDIM);
    const unsigned short* Vb = Vt + (size_t)bh * (HDIM * SEQ);

    const int m0 = blockIdx.y * 256 + wv * 64;

    auto stageKV = [&](int buf, int t) {
        const int kv0 = t * 64;
#pragma unroll
        for (int i = 0; i < 2; ++i) {
            const int o   = i * 4096 + tid * 16;
            const int row = o >> 7;
            const int in  = (o & 127) ^ ((row & 7) << 4);
            gload_lds16(Kb + (size_t)(kv0 + row) * HDIM + (in >> 1), &Kt[buf][o >> 1]);
            gload_lds16(Vb + (size_t)row * SEQ + kv0 + (in >> 1), &Vs[buf][o >> 1]);
        }
    };

    bf16x8 qf[4][2];
#pragma unroll
    for (int mt = 0; mt < 4; ++mt)
#pragma unroll
        for (int kc = 0; kc < 2; ++kc) {
            const int m = m0 + mt * 16 + (lane & 15);
            union { u32x4 u; bf16x8 v; } cv;
            cv.u = *reinterpret_cast<const u32x4*>(
                Qb + (size_t)m * HDIM + kc * 32 + g * 8);
            qf[mt][kc] = cv.v;
        }

    f32x4 oacc[4][4];
    float esum[4] = {0.f, 0.f, 0.f, 0.f};
#pragma unroll
    for (int mt = 0; mt < 4; ++mt)
#pragma unroll
        for (int x = 0; x < 4; ++x) oacc[mt][x] = (f32x4){0.f, 0.f, 0.f, 0.f};

    stageKV(0, 0);
    stageKV(1, 1);
    __syncthreads();

    for (int tt = 0; tt < 8; tt += 2) {
        if (tt < 6) {
            stageKV((tt + 2) & 3, tt + 2);
            stageKV((tt + 3) & 3, tt + 3);
        }

#pragma unroll
        for (int p = 0; p < 2; ++p) {
            const int cur = (tt + p) & 3;

            f32x4 sacc[4][4];
#pragma unroll
            for (int nt = 0; nt < 4; ++nt)
#pragma unroll
                for (int mt = 0; mt < 4; ++mt) sacc[nt][mt] = (f32x4){0.f, 0.f, 0.f, 0.f};

#pragma unroll
            for (int kc = 0; kc < 2; ++kc) {
                bf16x8 kf[4];
#pragma unroll
                for (int nt = 0; nt < 4; ++nt) {
                    const int kvl = nt * 16 + (lane & 15);
                    int byte = kvl * 128 + kc * 64 + g * 16;
                    byte ^= (kvl & 7) << 4;
                    kf[nt] = *reinterpret_cast<const bf16x8*>(
                        reinterpret_cast<const char*>(&Kt[cur][0]) + byte);
                }
                __builtin_amdgcn_s_setprio(1);
#pragma unroll
                for (int nt = 0; nt < 4; ++nt)
#pragma unroll
                    for (int mt = 0; mt < 4; ++mt)
                        sacc[nt][mt] = __builtin_amdgcn_mfma_f32_16x16x32_bf16(
                            kf[nt], qf[mt][kc], sacc[nt][mt], 0, 0, 0);
                __builtin_amdgcn_s_setprio(0);
            }

            bf16x8 pa[2][4];
#pragma unroll
            for (int c = 0; c < 2; ++c)
#pragma unroll
                for (int mt = 0; mt < 4; ++mt) {
                    float w[8];
#pragma unroll
                    for (int j = 0; j < 8; ++j) {
                        const float s  = sacc[2 * c + (j >> 2)][mt][j & 3];
                        const float a  = fabsf(s);
                        const float tt_ = __expf(a);
                        const float t2 = tt_ * tt_;
                        const float u  = __builtin_amdgcn_sqrtf(fmaf(s, s, 0.01f));
                        const float dl = u - a;                     // <= 0.1
                        const float ed = fmaf(dl, fmaf(dl, 0.5f, 1.0f), 1.0f);
                        const float eu = tt_ * ed;
                        esum[mt] += eu;
                        const float th = fmaf(-2.0f, __builtin_amdgcn_rcpf(t2 + 1.0f), 1.0f);
                        w[j] = __builtin_copysignf(th * eu, s);
                    }
                    union { unsigned int u[4]; bf16x8 v; } pk;
#pragma unroll
                    for (int pp = 0; pp < 4; ++pp)
                        pk.u[pp] = (__float_as_uint(w[2 * pp + 1]) & 0xffff0000u) |
                                   (__float_as_uint(w[2 * pp]) >> 16);
                    pa[c][mt] = pk.v;
                }

#pragma unroll
            for (int c = 0; c < 2; ++c) {
                bf16x8 vf[4];
#pragma unroll
                for (int dt = 0; dt < 4; ++dt) {
                    const int d = dt * 16 + (lane & 15);
                    const int swz = (d & 7) << 4;
                    const int rowb = d * 128;
                    uint2 lo = *reinterpret_cast<const uint2*>(
                        reinterpret_cast<const char*>(&Vs[cur][0]) +
                        (rowb + (((c * 32 + 4 * g) * 2) ^ swz)));
                    uint2 hi = *reinterpret_cast<const uint2*>(
                        reinterpret_cast<const char*>(&Vs[cur][0]) +
                        (rowb + (((c * 32 + 16 + 4 * g) * 2) ^ swz)));
                    union { unsigned int u[4]; bf16x8 v; } cvb;
                    cvb.u[0] = lo.x; cvb.u[1] = lo.y;
                    cvb.u[2] = hi.x; cvb.u[3] = hi.y;
                    vf[dt] = cvb.v;
                }
                __builtin_amdgcn_s_setprio(1);
#pragma unroll
                for (int mt = 0; mt < 4; ++mt)
#pragma unroll
                    for (int dt = 0; dt < 4; ++dt)
                        oacc[mt][dt] = __builtin_amdgcn_mfma_f32_16x16x32_bf16(
                            pa[c][mt], vf[dt], oacc[mt][dt], 0, 0, 0);
                __builtin_amdgcn_s_setprio(0);
            }
        }

        __syncthreads();
    }

    float rden[4];
#pragma unroll
    for (int mt = 0; mt < 4; ++mt) {
        float e = esum[mt];
        e += __shfl_xor(e, 16);
        e += __shfl_xor(e, 32);
        rden[mt] = __builtin_amdgcn_rcpf(e);
    }
    float rr_[4][4];
#pragma unroll
    for (int mt = 0; mt < 4; ++mt)
#pragma unroll
        for (int r = 0; r < 4; ++r)
            rr_[mt][r] = __shfl(rden[mt], g * 4 + r);

#pragma unroll
    for (int mt = 0; mt < 4; ++mt)
#pragma unroll
        for (int dt = 0; dt < 4; ++dt)
#pragma unroll
            for (int r = 0; r < 4; ++r) {
                const int m = m0 + mt * 16 + g * 4 + r;
                const int d = dt * 16 + (lane & 15);
                const float qv = bf2f(Qb[(size_t)m * HDIM + d]);
                outb[((size_t)b * SEQ + m) * SIZE_D + h * HDIM + d] =
                    f2bf(qv + oacc[mt][dt][r] * rr_[mt][r]);
            }
}

// ---------------------------------------------------------------------------
// LN0: bf16 in -> bf16 out, ONE WAVE PER ROW (no LDS, no barrier).
// 256 thr = 4 waves = 4 rows/block; grid NROWS/4.
// ---------------------------------------------------------------------------
__global__ __launch_bounds__(256) void ln0_bf16(const unsigned short* __restrict__ in,
                                                const float* __restrict__ w,
                                                const float* __restrict__ b,
                                                unsigned short* __restrict__ outb) {
    const int tid  = threadIdx.x;
    const int lane = tid & 63;
    const int row  = blockIdx.x * 4 + (tid >> 6);
    const size_t base = (size_t)row * SIZE_D + lane * 8;

    const ushort4 a0 = *reinterpret_cast<const ushort4*>(&in[base]);
    const ushort4 a1 = *reinterpret_cast<const ushort4*>(&in[base + 4]);
    float x[8];
    x[0] = bf2f(a0.x); x[1] = bf2f(a0.y); x[2] = bf2f(a0.z); x[3] = bf2f(a0.w);
    x[4] = bf2f(a1.x); x[5] = bf2f(a1.y); x[6] = bf2f(a1.z); x[7] = bf2f(a1.w);

    float s = 0.f, sq = 0.f;
#pragma unroll
    for (int j = 0; j < 8; ++j) { s += x[j]; sq += x[j] * x[j]; }
#pragma unroll
    for (int off = 32; off > 0; off >>= 1) {
        s  += __shfl_xor(s, off);
        sq += __shfl_xor(sq, off);
    }

    const float mu  = s * (1.0f / SIZE_D);
    const float var = sq * (1.0f / SIZE_D) - mu * mu;
    const float rr  = rsqrtf(var + 1e-5f);

    const float4 w0 = *reinterpret_cast<const float4*>(&w[lane * 8]);
    const float4 w1 = *reinterpret_cast<const float4*>(&w[lane * 8 + 4]);
    const float4 b0 = *reinterpret_cast<const float4*>(&b[lane * 8]);
    const float4 b1 = *reinterpret_cast<const float4*>(&b[lane * 8 + 4]);
    const float wa[8] = {w0.x, w0.y, w0.z, w0.w, w1.x, w1.y, w1.z, w1.w};
    const float ba[8] = {b0.x, b0.y, b0.z, b0.w, b1.x, b1.y, b1.z, b1.w};

    union { unsigned short s[8]; bf16x8 v; } o;
#pragma unroll
    for (int j = 0; j < 8; ++j)
        o.s[j] = f2bf((x[j] - mu) * rr * wa[j] + ba[j]);
    *reinterpret_cast<bf16x8*>(&outb[base]) = o.v;
}

// ---------------------------------------------------------------------------
// Fused out-proj + ReLU + residual + LN1 -> d_out. (r17 shell)
// BM=32 (grid 512 -> 2 blocks/CU, 4 waves/SIMD), BK=32.
// ---------------------------------------------------------------------------
__global__ __launch_bounds__(512, 2) void oproj_ln(const unsigned short* __restrict__ X,
                                                   const unsigned short* __restrict__ W,
                                                   const float* __restrict__ bo,
                                                   const float* __restrict__ g1,
                                                   const float* __restrict__ b1,
                                                   float* __restrict__ out) {
    __shared__ __align__(16) unsigned short Ad[2][32 * 32];
    __shared__ __align__(16) unsigned short Bd[2][512 * 32];
    __shared__ float red[32][8][2];
    __shared__ float stat[32][2];

    const int tid  = threadIdx.x;
    const int wv   = tid >> 6;
    const int lane = tid & 63;
    const int bm   = blockIdx.x * 32;

    auto stage = [&](int buf, int t) {
        const int k0 = t * 32;
        if (tid < 128) {
            const int o   = tid * 16;
            const int row = o >> 6;
            const int in  = (o & 63) ^ (((row >> 1) & 3) << 4);
            gload_lds16(X + (size_t)(bm + row) * SIZE_D + k0 + (in >> 1), &Ad[buf][o >> 1]);
        }
#pragma unroll
        for (int i = 0; i < 4; ++i) {
            const int o   = i * 8192 + tid * 16;
            const int row = o >> 6;
            const int in  = (o & 63) ^ (((row >> 1) & 3) << 4);
            gload_lds16(W + (size_t)row * SIZE_D + k0 + (in >> 1), &Bd[buf][o >> 1]);
        }
    };

    f32x4 acc[2][4];
#pragma unroll
    for (int mt = 0; mt < 2; ++mt)
#pragma unroll
        for (int nt = 0; nt < 4; ++nt) acc[mt][nt] = (f32x4){0.f, 0.f, 0.f, 0.f};

    stage(0, 0);
    __syncthreads();
    int cur = 0;

    for (int t = 0; t < 16; ++t) {
        if (t < 15) stage(cur ^ 1, t + 1);

        bf16x8 af[2], bfr[4];
#pragma unroll
        for (int mt = 0; mt < 2; ++mt) {
            const int r = mt * 16 + (lane & 15);
            int byte = r * 64 + (lane >> 4) * 16;
            byte ^= ((r >> 1) & 3) << 4;
            af[mt] = *reinterpret_cast<const bf16x8*>(
                reinterpret_cast<const char*>(&Ad[cur][0]) + byte);
        }
#pragma unroll
        for (int nt = 0; nt < 4; ++nt) {
            const int r = wv * 64 + nt * 16 + (lane & 15);
            int byte = r * 64 + (lane >> 4) * 16;
            byte ^= ((r >> 1) & 3) << 4;
            bfr[nt] = *reinterpret_cast<const bf16x8*>(
                reinterpret_cast<const char*>(&Bd[cur][0]) + byte);
        }
#pragma unroll
        for (int mt = 0; mt < 2; ++mt)
#pragma unroll
            for (int nt = 0; nt < 4; ++nt)
                acc[mt][nt] = __builtin_amdgcn_mfma_f32_16x16x32_bf16(
                    af[mt], bfr[nt], acc[mt][nt], 0, 0, 0);

        __syncthreads();
        cur ^= 1;
    }

#pragma unroll
    for (int nt = 0; nt < 4; ++nt) {
        const int n  = wv * 64 + nt * 16 + (lane & 15);
        const float bc = bo[n];
#pragma unroll
        for (int mt = 0; mt < 2; ++mt) {
            const int row0 = bm + mt * 16 + (lane >> 4) * 4;
#pragma unroll
            for (int r = 0; r < 4; ++r) {
                const float R = bf2f(X[(size_t)(row0 + r) * SIZE_D + n]);
                acc[mt][nt][r] = R + fmaxf(acc[mt][nt][r] + bc, 0.0f);
            }
        }
    }

    float ps[2][4], pq[2][4];
#pragma unroll
    for (int mt = 0; mt < 2; ++mt)
#pragma unroll
        for (int r = 0; r < 4; ++r) {
            float s = 0.f, q = 0.f;
#pragma unroll
            for (int nt = 0; nt < 4; ++nt) {
                const float v = acc[mt][nt][r];
                s += v; q += v * v;
            }
#pragma unroll
            for (int off = 1; off <= 8; off <<= 1) {
                s += __shfl_xor(s, off);
                q += __shfl_xor(q, off);
            }
            ps[mt][r] = s; pq[mt][r] = q;
        }
    if ((lane & 15) < 8) {
        const int mtw = (lane & 15) >> 2;
        const int rw  = lane & 3;
        const int rowL = mtw * 16 + (lane >> 4) * 4 + rw;
        red[rowL][wv][0] = ps[mtw][rw];
        red[rowL][wv][1] = pq[mtw][rw];
    }
    __syncthreads();
    if (tid < 32) {
        float s = 0.f, q = 0.f;
#pragma unroll
        for (int w8 = 0; w8 < 8; ++w8) { s += red[tid][w8][0]; q += red[tid][w8][1]; }
        const float mu  = s * (1.0f / SIZE_D);
        const float var = q * (1.0f / SIZE_D) - mu * mu;
        stat[tid][0] = mu;
        stat[tid][1] = rsqrtf(var + 1e-5f);
    }
    __syncthreads();

#pragma unroll
    for (int nt = 0; nt < 4; ++nt) {
        const int n = wv * 64 + nt * 16 + (lane & 15);
        const float g = g1[n], bb = b1[n];
#pragma unroll
        for (int mt = 0; mt < 2; ++mt) {
#pragma unroll
            for (int r = 0; r < 4; ++r) {
                const int rowL = mt * 16 + (lane >> 4) * 4 + r;
                const float y = (acc[mt][nt][r] - stat[rowL][0]) * stat[rowL][1];
                out[(size_t)(bm + rowL) * SIZE_D + n] = y * g + bb;
            }
        }
    }
}

// ---------------------------------------------------------------------------
extern "C" void kernel_launch(void* const* d_in, const int* in_sizes, int n_in,
                              void* d_out, int out_size, void* d_ws, size_t ws_size,
                              hipStream_t stream) {
    const float* query = (const float*)d_in[0];
    const float* keyv  = (const float*)d_in[1];
    const float* Wq    = (const float*)d_in[2];
    const float* bq    = (const float*)d_in[3];
    const float* Wk    = (const float*)d_in[4];
    const float* bk    = (const float*)d_in[5];
    const float* Wv    = (const float*)d_in[6];
    const float* bv    = (const float*)d_in[7];
    const float* Wo    = (const float*)d_in[8];
    const float* bo    = (const float*)d_in[9];
    const float* ln0w  = (const float*)d_in[10];
    const float* ln0b  = (const float*)d_in[11];
    const float* ln1w  = (const float*)d_in[12];
    const float* ln1b  = (const float*)d_in[13];
    float* out = (float*)d_out;

    // workspace layout:
    //   [ 0,16) obf bf16 (attn output + residual)
    //   [32,48) Qh bf16 head-major -> Xbf bf16 after ln0
    //   [48,64) Kh bf16 head-major (pre-scaled)
    //   [64,80) Vt bf16 transposed [b,h,d,kv]
    //   [80,82) Wbf: [Wq;Wk;Wv;Wo] bf16 contiguous
    char* ws = (char*)d_ws;
    unsigned short* obf  = (unsigned short*)ws;
    unsigned short* Qh   = (unsigned short*)(ws + ((size_t)32 << 20));
    unsigned short* Xbf  = Qh;
    unsigned short* Kh   = (unsigned short*)(ws + ((size_t)48 << 20));
    unsigned short* Vt   = (unsigned short*)(ws + ((size_t)64 << 20));
    unsigned short* Wbf  = (unsigned short*)(ws + ((size_t)80 << 20));
    unsigned short* WoB  = Wbf + 786432;

    cvt_w4<<<dim3(64, 4), 256, 0, stream>>>(Wq, Wk, Wv, Wo, Wbf);

    gemm_proj3<<<dim3(128, 12), 256, 0, stream>>>(query, keyv, Wbf, bq, bk, bv, Qh, Kh, Vt);

    attn_mfma<<<dim3(BATCH * HEADS, 2), 256, 0, stream>>>(Qh, Kh, Vt, obf);

    ln0_bf16<<<NROWS / 4, 256, 0, stream>>>(obf, ln0w, ln0b, Xbf);

    oproj_ln<<<NROWS / 32, 512, 0, stream>>>(Xbf, WoB, bo, ln1w, ln1b, out);
}